// Round 6
// baseline (204.703 us; speedup 1.0000x reference)
//
#include <hip/hip_runtime.h>

typedef unsigned short u16;
typedef unsigned int   u32;

typedef __attribute__((ext_vector_type(8))) short short8;   // 8 bf16 (4 VGPRs)
typedef __attribute__((ext_vector_type(4))) float f32x4;    // MFMA acc

union Frag { u32 u[4]; short8 s; };

__device__ __forceinline__ u32 fbits(float f){ union{float f;u32 u;}x; x.f=f; return x.u; }
__device__ __forceinline__ float bitsf(u32 u){ union{u32 u;float f;}x; x.u=u; return x.f; }
__device__ __forceinline__ u32 pack_trunc(float a, float b){
    return __builtin_amdgcn_perm(fbits(b), fbits(a), 0x07060302u);
}
__device__ __forceinline__ u32 bf16_rne(float a){
    u32 u = fbits(a); return (u + 0x7FFFu + ((u >> 16) & 1u)) >> 16;
}
__device__ __forceinline__ u32 pack_rne(float a, float b){
    return bf16_rne(a) | (bf16_rne(b) << 16);
}
__device__ __forceinline__ float sigmoidf_(float x){
    return __builtin_amdgcn_rcpf(1.0f + __expf(-x));
}

#define LOG2E 1.4426950408889634f

// Row-split GRU, 2 batch-pairs per wave (round 6). 4 waves; wave w owns h
// rows 16w..16w+15 for BOTH pairs (4 batches/block, 512 blocks). Weights
// (A-frags, biases) shared across pairs; per-step overhead and barriers
// amortized 2x; two independent MFMA/gate chains per wave double ILP.
// launch_bounds(256,2): VGPR cap 256 (peak live ~164, no spill — round-3
// lesson); occupancy is 2 blocks/CU (LDS 59.9KB) regardless.
// Numerics identical to round 5 per batch (canary 0.001953125).
struct __align__(16) SharedMem {
    union {
        struct {                       // loop state: 51,200 B
            u16 hh[2][2][16][72];      // [pair][buf][seq][k] h hi-bf16
            u16 hl[2][2][16][72];      // [pair][buf][seq][k] h lo-bf16
            u32 uallp[2][64][16][4];   // [pair][t][s] {uh01,uh23,ul01,ul23}
        } lp;
        struct {                       // tail: 13,572 B
            float wl[1152];
            float bl[16];
            float wcf[640];
            float bcf[20];
            float wcc[80];
            float bcc[20];
            float wcm[400];
            float bcm[20];
            float wfin[20];
            float bfin;
            float line[4][128];
            float pp[4][128];
        } tl;
    };
    float h[32 * 68];                  // final h (f32) for the tail, 8,704 B
};

__global__ __launch_bounds__(256, 2)
void FRAPRQ_fused_kernel(
    const float* __restrict__ feat,       // (B,16)
    const float* __restrict__ hist,       // (B,64,24)
    const int*   __restrict__ relation,   // (8,7)
    const float* __restrict__ emb_phase,  // (2,4)
    const float* __restrict__ Wv,         // (4,1)
    const float* __restrict__ bv,         // (4)
    const float* __restrict__ Wh,         // (4,3)
    const float* __restrict__ bh,         // (4)
    const float* __restrict__ Wih,        // (192,4)
    const float* __restrict__ Whh,        // (192,64)
    const float* __restrict__ bih,        // (192)
    const float* __restrict__ bhh,        // (192)
    const float* __restrict__ Wl,         // (16,72)
    const float* __restrict__ bl,         // (16)
    const float* __restrict__ emb_const,  // (2,4)
    const float* __restrict__ Wcf,        // (20,32)
    const float* __restrict__ bcf,        // (20)
    const float* __restrict__ Wcc,        // (20,4)
    const float* __restrict__ bcc,        // (20)
    const float* __restrict__ Wcm,        // (20,20)
    const float* __restrict__ bcm,        // (20)
    const float* __restrict__ Wfin,      // (1,20)
    const float* __restrict__ bfin,      // (1)
    float* __restrict__ out)             // (B,8)
{
    __shared__ SharedMem sm;
    const int tid  = threadIdx.x;        // 0..255
    const int w    = tid >> 6;           // wave 0..3: owns h rows 16w..16w+15
    const int lane = tid & 63;
    const int sq   = lane & 15;          // MFMA column: local seq (2 b's x 8 lanes)
    const int q    = lane >> 4;          // MFMA quad
    const int b_base = blockIdx.x * 4;   // 4 batches = 2 pairs per block

    // ---- cooperative staging ----
    {   // zero all h ping-pong buffers (h(-1) = 0); hh/hl adjacent: 4608 u32
        u32* z = (u32*)&sm.lp.hh[0][0][0][0];
        #pragma unroll 1
        for (int i = tid; i < 4608; i += 256) z[i] = 0u;
    }

    // ---- u precompute + bf16 hi/lo pack: thread = (pair, seq, t-group) ----
    {
        const int s  = tid & 15;         // seq within pair
        const int pr = (tid >> 4) & 1;   // pair
        const int tg = tid >> 5;         // 0..7 -> t = 8*tg + i
        const int bs_ = b_base + pr * 2 + (s >> 3), ls_ = s & 7;
        const float* hbp = hist + (size_t)bs_ * 1536;
        float whc[12], bhc[4];
        #pragma unroll
        for (int c = 0; c < 4; ++c){
            whc[c*3+0] = Wh[c*3+0]; whc[c*3+1] = Wh[c*3+1]; whc[c*3+2] = Wh[c*3+2];
            bhc[c] = bh[c];
        }
        #pragma unroll
        for (int i = 0; i < 8; ++i){
            const int t = tg * 8 + i;
            const float x0 = hbp[t*24 + ls_];
            const float x1 = hbp[t*24 + ls_ + 8];
            const float x2 = hbp[t*24 + ls_ + 16];
            float u_[4];
            #pragma unroll
            for (int c = 0; c < 4; ++c)
                u_[c] = sigmoidf_(fmaf(whc[c*3], x0, fmaf(whc[c*3+1], x1, fmaf(whc[c*3+2], x2, bhc[c]))));
            const u32 uh01 = pack_rne(u_[0], u_[1]);
            const u32 uh23 = pack_rne(u_[2], u_[3]);
            const float l0 = u_[0] - bitsf((uh01 & 0xFFFFu) << 16);
            const float l1 = u_[1] - bitsf(uh01 & 0xFFFF0000u);
            const float l2 = u_[2] - bitsf((uh23 & 0xFFFFu) << 16);
            const float l3 = u_[3] - bitsf(uh23 & 0xFFFF0000u);
            *(uint4*)&sm.lp.uallp[pr][t][s][0] =
                make_uint4(uh01, uh23, pack_rne(l0, l1), pack_rne(l2, l3));
        }
    }

    // gate scales: r/z sigmoid(x)=rcp(1+exp2(-log2e*x)); n tanh via +2log2e
    const float gsc[3] = { -LOG2E, -LOG2E, 2.0f * LOG2E };

    // ---- Whh A-fragments (prescaled, shared by both pairs) ----
    Frag ahi[6], alo[6];
    #pragma unroll
    for (int g3 = 0; g3 < 3; ++g3){
        #pragma unroll
        for (int c = 0; c < 2; ++c){
            const int idx = g3 * 2 + c;
            const float* wp = Whh + (64 * g3 + 16 * w + sq) * 64 + 32 * c + 8 * q;
            const float4 fA = *(const float4*)wp;
            const float4 fB = *(const float4*)(wp + 4);
            const float s3 = gsc[g3];
            const float f[8] = {fA.x*s3, fA.y*s3, fA.z*s3, fA.w*s3,
                                fB.x*s3, fB.y*s3, fB.z*s3, fB.w*s3};
            #pragma unroll
            for (int p = 0; p < 4; ++p){
                const u32 hi = pack_rne(f[2*p], f[2*p+1]);
                ahi[idx].u[p] = hi;
                const float l0 = f[2*p]   - bitsf((hi & 0xFFFFu) << 16);
                const float l1 = f[2*p+1] - bitsf(hi & 0xFFFF0000u);
                alo[idx].u[p] = pack_rne(l0, l1);
            }
        }
    }

    // ---- Wih A-fragments (prescaled, hi/lo folded along K; shared) ----
    Frag auR, auZ, auN;
    {
        Frag* dst[3] = { &auR, &auZ, &auN };
        #pragma unroll
        for (int g3 = 0; g3 < 3; ++g3){
            const int row = 64 * g3 + 16 * w + sq;
            const float4 wv4 = *(const float4*)&Wih[row * 4];
            const float s3 = gsc[g3];
            const float v0 = wv4.x*s3, v1 = wv4.y*s3, v2 = wv4.z*s3, v3 = wv4.w*s3;
            const u32 whi01 = pack_rne(v0, v1);
            const u32 whi23 = pack_rne(v2, v3);
            const float r0 = v0 - bitsf((whi01 & 0xFFFFu) << 16);
            const float r1 = v1 - bitsf(whi01 & 0xFFFF0000u);
            const float r2 = v2 - bitsf((whi23 & 0xFFFFu) << 16);
            const float r3 = v3 - bitsf(whi23 & 0xFFFF0000u);
            const u32 wlo01 = pack_rne(r0, r1);
            const u32 wlo23 = pack_rne(r2, r3);
            dst[g3]->u[0] = (q <= 1) ? whi01 : 0u;
            dst[g3]->u[1] = (q <= 1) ? whi23 : 0u;
            dst[g3]->u[2] = (q == 0) ? wlo01 : 0u;
            dst[g3]->u[3] = (q == 0) ? wlo23 : 0u;
        }
    }

    // ---- per-lane bias C-vectors (prescaled; shared) rows j = 16w+4q+r ----
    f32x4 bR4, bZ4, bNh4, bNi4;
    #pragma unroll
    for (int r = 0; r < 4; ++r){
        const int j = 16 * w + 4 * q + r;
        bR4[r]  = -LOG2E * (bih[j]       + bhh[j]);
        bZ4[r]  = -LOG2E * (bih[64 + j]  + bhh[64 + j]);
        bNi4[r] = 2.0f * LOG2E * bih[128 + j];
        bNh4[r] = 2.0f * LOG2E * bhh[128 + j];
    }

    float hreg[2][4] = {{0.f,0.f,0.f,0.f},{0.f,0.f,0.f,0.f}};

    __syncthreads();   // staging + h init + uallp visible

    #define MFMA_(A,B,C) __builtin_amdgcn_mfma_f32_16x16x32_bf16(A, B, C, 0, 0, 0)

    #pragma unroll 1
    for (int t = 0; t < 64; ++t){
        const int rb = t & 1;          // read h(t-1) from buf rb, write to rb^1

        // B fragments for BOTH pairs first (fills the LDS queue)
        short8 bh0[2], bl0[2], bh1[2], bl1[2];
        Frag bu[2];
        #pragma unroll
        for (int p = 0; p < 2; ++p){
            bh0[p] = *(const short8*)&sm.lp.hh[p][rb][sq][8 * q];
            bl0[p] = *(const short8*)&sm.lp.hl[p][rb][sq][8 * q];
            bh1[p] = *(const short8*)&sm.lp.hh[p][rb][sq][32 + 8 * q];
            bl1[p] = *(const short8*)&sm.lp.hl[p][rb][sq][32 + 8 * q];
            const uint4 uv = *(const uint4*)&sm.lp.uallp[p][t][sq][0];
            bu[p].u[0] = (q == 0) ? uv.x : ((q == 1) ? uv.z : 0u);
            bu[p].u[1] = (q == 0) ? uv.y : ((q == 1) ? uv.w : 0u);
            bu[p].u[2] = (q == 0) ? uv.x : 0u;
            bu[p].u[3] = (q == 0) ? uv.y : 0u;
        }

        // per pair: 21 MFMAs (4 chains) + gates + pack + write
        #pragma unroll
        for (int p = 0; p < 2; ++p){
            f32x4 aR = MFMA_(auR.s, bu[p].s, bR4);
            aR = MFMA_(ahi[0].s, bh0[p], aR); aR = MFMA_(ahi[0].s, bl0[p], aR); aR = MFMA_(alo[0].s, bh0[p], aR);
            aR = MFMA_(ahi[1].s, bh1[p], aR); aR = MFMA_(ahi[1].s, bl1[p], aR); aR = MFMA_(alo[1].s, bh1[p], aR);
            f32x4 aZ = MFMA_(auZ.s, bu[p].s, bZ4);
            aZ = MFMA_(ahi[2].s, bh0[p], aZ); aZ = MFMA_(ahi[2].s, bl0[p], aZ); aZ = MFMA_(alo[2].s, bh0[p], aZ);
            aZ = MFMA_(ahi[3].s, bh1[p], aZ); aZ = MFMA_(ahi[3].s, bl1[p], aZ); aZ = MFMA_(alo[3].s, bh1[p], aZ);
            f32x4 aN = MFMA_(ahi[4].s, bh0[p], bNh4);
            aN = MFMA_(ahi[4].s, bl0[p], aN); aN = MFMA_(alo[4].s, bh0[p], aN);
            aN = MFMA_(ahi[5].s, bh1[p], aN); aN = MFMA_(ahi[5].s, bl1[p], aN); aN = MFMA_(alo[5].s, bh1[p], aN);
            f32x4 gN = MFMA_(auN.s, bu[p].s, bNi4);

            float hn4[4];
            #pragma unroll
            for (int r = 0; r < 4; ++r){
                const float rr   = __builtin_amdgcn_rcpf(1.0f + __builtin_amdgcn_exp2f(aR[r]));
                const float zz   = __builtin_amdgcn_rcpf(1.0f + __builtin_amdgcn_exp2f(aZ[r]));
                const float y    = fmaf(rr, aN[r], gN[r]);
                const float cand = fmaf(-2.0f,
                    __builtin_amdgcn_rcpf(__builtin_amdgcn_exp2f(y) + 1.0f), 1.0f);
                const float hn   = fmaf(zz, hreg[p][r] - cand, cand);
                hreg[p][r] = hn;
                hn4[r] = hn;
            }

            const u32 hi0 = pack_trunc(hn4[0], hn4[1]);
            const u32 hi1 = pack_trunc(hn4[2], hn4[3]);
            const float l0 = hn4[0] - bitsf((hi0 & 0xFFFFu) << 16);
            const float l1 = hn4[1] - bitsf(hi0 & 0xFFFF0000u);
            const float l2 = hn4[2] - bitsf((hi1 & 0xFFFFu) << 16);
            const float l3 = hn4[3] - bitsf(hi1 & 0xFFFF0000u);
            const u32 lo0 = pack_trunc(l0, l1);
            const u32 lo1 = pack_trunc(l2, l3);
            const int wb = rb ^ 1;
            *(uint2*)&sm.lp.hh[p][wb][sq][16 * w + 4 * q] = make_uint2(hi0, hi1);
            *(uint2*)&sm.lp.hl[p][wb][sq][16 * w + 4 * q] = make_uint2(lo0, lo1);
        }

        __syncthreads();   // single barrier per step covers both pairs
    }
    #undef MFMA_

    // ---- final h (f32) for the tail: rows [pair*16 + sq] ----
    #pragma unroll
    for (int p = 0; p < 2; ++p){
        const float4 hv = make_float4(hreg[p][0], hreg[p][1], hreg[p][2], hreg[p][3]);
        *(float4*)&sm.h[(p * 16 + sq) * 68 + 16 * w + 4 * q] = hv;
    }

    // ---- stage tail weights into the (dead) loop region ----
    for (int i = tid; i < 1152; i += 256) sm.tl.wl[i]  = Wl[i];
    for (int i = tid; i <  640; i += 256) sm.tl.wcf[i] = Wcf[i];
    for (int i = tid; i <  400; i += 256) sm.tl.wcm[i] = Wcm[i];
    if (tid < 80) sm.tl.wcc[tid] = Wcc[tid];
    if (tid < 20){
        sm.tl.bcf[tid]  = bcf[tid];
        sm.tl.bcc[tid]  = bcc[tid];
        sm.tl.bcm[tid]  = bcm[tid];
        sm.tl.wfin[tid] = Wfin[tid];
    }
    if (tid < 16) sm.tl.bl[tid] = bl[tid];
    if (tid == 0) sm.tl.bfin = bfin[0];
    __syncthreads();   // h writes + tail weights visible

    // ---- tail: wave w handles batch b_base + w end-to-end ----
    {
        const int b = b_base + w;
        // Phase A: 16 line outputs x 8 lanes; each lane does 2
        const int l = lane >> 3, o = lane & 7;
        float fv[8];
        const float vraw = feat[b * 16 + 8 + l];
        const int   bit  = ((int)feat[b * 16 + l]) & 1;
        #pragma unroll
        for (int c = 0; c < 4; ++c){
            fv[c]     = sigmoidf_(fmaf(vraw, Wv[c], bv[c]));
            fv[4 + c] = sigmoidf_(emb_phase[bit * 4 + c]);
        }
        // batch w's h rows: pair = w>>1, half = w&1 -> row (w>>1)*16+(w&1)*8+l
        const float* hrow = &sm.h[((w >> 1) * 16 + (w & 1) * 8 + l) * 68];
        #pragma unroll
        for (int half = 0; half < 2; ++half){
            const int oo = o + half * 8;
            float acc = sm.tl.bl[oo];
            #pragma unroll
            for (int f = 0; f < 8; ++f) acc = fmaf(fv[f], sm.tl.wl[oo * 72 + f], acc);
            for (int k = 0; k < 64; ++k) acc = fmaf(hrow[k], sm.tl.wl[oo * 72 + 8 + k], acc);
            sm.tl.line[w][l * 16 + oo] = fmaxf(acc, 0.0f);
        }
        __builtin_amdgcn_wave_barrier();
        // Phase B (wave-private)
        {
            const int p = lane >> 3, oo = lane & 7;
            const int l0 = (0x64204501u >> (p * 4)) & 15;
            const int l1 = (0x75316723u >> (p * 4)) & 15;
            sm.tl.pp[w][p * 16 + oo]     = sm.tl.line[w][l0 * 16 + oo]     + sm.tl.line[w][l1 * 16 + oo];
            sm.tl.pp[w][p * 16 + oo + 8] = sm.tl.line[w][l0 * 16 + oo + 8] + sm.tl.line[w][l1 * 16 + oo + 8];
        }
        __builtin_amdgcn_wave_barrier();
        // Phase C (wave-private)
        if (lane < 56){
            const int p  = lane / 7;
            const int qi = lane - p * 7;
            const int jl = qi + (qi >= p ? 1 : 0);
            float fmv[32];
            #pragma unroll
            for (int f = 0; f < 16; ++f){
                fmv[f]      = sm.tl.pp[w][p  * 16 + f];
                fmv[16 + f] = sm.tl.pp[w][jl * 16 + f];
            }
            const int rel = relation[p * 7 + qi] & 1;
            float ce[4];
            #pragma unroll
            for (int c = 0; c < 4; ++c) ce[c] = emb_const[rel * 4 + c];
            float m[20];
            for (int o2 = 0; o2 < 20; ++o2){
                float xf = sm.tl.bcf[o2];
                #pragma unroll
                for (int f = 0; f < 32; ++f) xf = fmaf(fmv[f], sm.tl.wcf[o2 * 32 + f], xf);
                float yc = sm.tl.bcc[o2];
                #pragma unroll
                for (int c = 0; c < 4; ++c) yc = fmaf(ce[c], sm.tl.wcc[o2 * 4 + c], yc);
                m[o2] = fmaxf(xf, 0.0f) * fmaxf(yc, 0.0f);
            }
            float fin = sm.tl.bfin;
            for (int o2 = 0; o2 < 20; ++o2){
                float zz = sm.tl.bcm[o2];
                #pragma unroll
                for (int c = 0; c < 20; ++c) zz = fmaf(m[c], sm.tl.wcm[o2 * 20 + c], zz);
                fin = fmaf(fmaxf(zz, 0.0f), sm.tl.wfin[o2], fin);
            }
            sm.tl.line[w][lane] = fin;   // line dead after Phase B
        }
        __builtin_amdgcn_wave_barrier();
        if (lane < 8){
            float acc = 0.0f;
            #pragma unroll
            for (int qq = 0; qq < 7; ++qq) acc += sm.tl.line[w][lane * 7 + qq];
            out[b * 8 + lane] = acc;
        }
    }
}

extern "C" void kernel_launch(void* const* d_in, const int* in_sizes, int n_in,
                              void* d_out, int out_size, void* d_ws, size_t ws_size,
                              hipStream_t stream) {
    (void)n_in; (void)d_ws; (void)ws_size; (void)out_size;
    const float* feat      = (const float*)d_in[0];
    const float* hist      = (const float*)d_in[1];
    const int*   relation  = (const int*)d_in[2];
    const float* emb_phase = (const float*)d_in[3];
    const float* Wv        = (const float*)d_in[4];
    const float* bv        = (const float*)d_in[5];
    const float* Wh        = (const float*)d_in[6];
    const float* bh        = (const float*)d_in[7];
    const float* Wih       = (const float*)d_in[8];
    const float* Whh       = (const float*)d_in[9];
    const float* bih       = (const float*)d_in[10];
    const float* bhh       = (const float*)d_in[11];
    const float* Wl        = (const float*)d_in[12];
    const float* bl        = (const float*)d_in[13];
    const float* emb_const = (const float*)d_in[14];
    const float* Wcf       = (const float*)d_in[15];
    const float* bcf       = (const float*)d_in[16];
    const float* Wcc       = (const float*)d_in[17];
    const float* bcc       = (const float*)d_in[18];
    const float* Wcm       = (const float*)d_in[19];
    const float* bcm       = (const float*)d_in[20];
    const float* Wfin      = (const float*)d_in[21];
    const float* bfin      = (const float*)d_in[22];
    float* out = (float*)d_out;

    const int B = in_sizes[0] / 16;     // 2048
    const int nblocks = B / 4;          // 512 blocks: 2 pairs (4 batches) each
    FRAPRQ_fused_kernel<<<nblocks, 256, 0, stream>>>(
        feat, hist, relation, emb_phase, Wv, bv, Wh, bh, Wih, Whh, bih, bhh,
        Wl, bl, emb_const, Wcf, bcf, Wcc, bcc, Wcm, bcm, Wfin, bfin, out);
}

// Round 7
// 198.444 us; speedup vs baseline: 1.0315x; 1.0315x over previous
//
#include <hip/hip_runtime.h>

typedef unsigned short u16;
typedef unsigned int   u32;

typedef __attribute__((ext_vector_type(8))) short short8;   // 8 bf16 (4 VGPRs)
typedef __attribute__((ext_vector_type(4))) float f32x4;    // MFMA acc

union Frag { u32 u[4]; short8 s; };

__device__ __forceinline__ u32 fbits(float f){ union{float f;u32 u;}x; x.f=f; return x.u; }
__device__ __forceinline__ float bitsf(u32 u){ union{u32 u;float f;}x; x.u=u; return x.f; }
__device__ __forceinline__ u32 pack_trunc(float a, float b){
    return __builtin_amdgcn_perm(fbits(b), fbits(a), 0x07060302u);
}
__device__ __forceinline__ u32 bf16_rne(float a){
    u32 u = fbits(a); return (u + 0x7FFFu + ((u >> 16) & 1u)) >> 16;
}
__device__ __forceinline__ u32 pack_rne(float a, float b){
    return bf16_rne(a) | (bf16_rne(b) << 16);
}
__device__ __forceinline__ float sigmoidf_(float x){
    return __builtin_amdgcn_rcpf(1.0f + __expf(-x));
}

#define LOG2E 1.4426950408889634f

// Row-split GRU: 4 waves, wave w owns h rows 16w..16w+15, full K=64, no
// partial exchange. h(t) pre-packed bf16 hi/lo in ping-pong LDS; ds_read IS
// the MFMA B-fragment. Round-7 = round-5 structure EXACTLY (1 pair/wave,
// 1024 blocks, 16 waves/CU — round-6 showed TLP beats per-wave ILP here)
// plus two scheduling-only changes:
//  - pure x2 t-unroll: rb is a literal (buffer addrs strength-reduce).
//    Verbatim body duplication — NO register rotation (round-2 lesson).
//  - s_setprio(1) around the MFMA cluster (T5: blocks per SIMD are
//    independent/dephased -> scheduler can favor the MFMA-entering wave).
// Numerics bit-identical to round 5 (canary 0.001953125).
struct __align__(16) SharedMem {
    union {
        struct {                       // loop state: 25,600 B
            u16 hh[2][16][72];         // h hi-bf16, ping-pong [buf][seq][k]
            u16 hl[2][16][72];         // h lo-bf16
            u32 uallp[64][16][4];      // packed u: {uh01,uh23,ul01,ul23} (16 KB)
        } lp;
        struct {                       // tail: 11,524 B
            float wl[1152];
            float bl[16];
            float wcf[640];
            float bcf[20];
            float wcc[80];
            float bcc[20];
            float wcm[400];
            float bcm[20];
            float wfin[20];
            float bfin;
            float line[2][128];
            float pp[2][128];
        } tl;
    };
    float h[16 * 68];                  // final h (f32) for the tail, 4352 B
};

__global__ __launch_bounds__(256, 4)
void FRAPRQ_fused_kernel(
    const float* __restrict__ feat,       // (B,16)
    const float* __restrict__ hist,       // (B,64,24)
    const int*   __restrict__ relation,   // (8,7)
    const float* __restrict__ emb_phase,  // (2,4)
    const float* __restrict__ Wv,         // (4,1)
    const float* __restrict__ bv,         // (4)
    const float* __restrict__ Wh,         // (4,3)
    const float* __restrict__ bh,         // (4)
    const float* __restrict__ Wih,        // (192,4)
    const float* __restrict__ Whh,        // (192,64)
    const float* __restrict__ bih,        // (192)
    const float* __restrict__ bhh,        // (192)
    const float* __restrict__ Wl,         // (16,72)
    const float* __restrict__ bl,         // (16)
    const float* __restrict__ emb_const,  // (2,4)
    const float* __restrict__ Wcf,        // (20,32)
    const float* __restrict__ bcf,        // (20)
    const float* __restrict__ Wcc,        // (20,4)
    const float* __restrict__ bcc,        // (20)
    const float* __restrict__ Wcm,        // (20,20)
    const float* __restrict__ bcm,        // (20)
    const float* __restrict__ Wfin,      // (1,20)
    const float* __restrict__ bfin,      // (1)
    float* __restrict__ out)             // (B,8)
{
    __shared__ SharedMem sm;
    const int tid  = threadIdx.x;        // 0..255
    const int w    = tid >> 6;           // wave 0..3: owns h rows 16w..16w+15
    const int lane = tid & 63;
    const int sq   = lane & 15;          // MFMA column: local seq (2 b's x 8 lanes)
    const int q    = lane >> 4;          // MFMA quad
    const int b_base = blockIdx.x * 2;

    // ---- cooperative staging ----
    {   // zero both hi/lo ping-pong h buffers (h(-1) = 0); hh/hl adjacent
        u32* z = (u32*)&sm.lp.hh[0][0][0];
        #pragma unroll 1
        for (int i = tid; i < 2304; i += 256) z[i] = 0u;
    }

    // ---- u precompute + bf16 hi/lo pack: thread = (seq s, t-group) ----
    {
        const int s  = tid & 15;         // seq
        const int tg = tid >> 4;         // 0..15 -> t = 4*tg + i
        const int bs_ = b_base + (s >> 3), ls_ = s & 7;
        const float* hbp = hist + (size_t)bs_ * 1536;
        float whc[12], bhc[4];
        #pragma unroll
        for (int c = 0; c < 4; ++c){
            whc[c*3+0] = Wh[c*3+0]; whc[c*3+1] = Wh[c*3+1]; whc[c*3+2] = Wh[c*3+2];
            bhc[c] = bh[c];
        }
        #pragma unroll
        for (int i = 0; i < 4; ++i){
            const int t = tg * 4 + i;
            const float x0 = hbp[t*24 + ls_];
            const float x1 = hbp[t*24 + ls_ + 8];
            const float x2 = hbp[t*24 + ls_ + 16];
            float u_[4];
            #pragma unroll
            for (int c = 0; c < 4; ++c)
                u_[c] = sigmoidf_(fmaf(whc[c*3], x0, fmaf(whc[c*3+1], x1, fmaf(whc[c*3+2], x2, bhc[c]))));
            const u32 uh01 = pack_rne(u_[0], u_[1]);
            const u32 uh23 = pack_rne(u_[2], u_[3]);
            const float l0 = u_[0] - bitsf((uh01 & 0xFFFFu) << 16);
            const float l1 = u_[1] - bitsf(uh01 & 0xFFFF0000u);
            const float l2 = u_[2] - bitsf((uh23 & 0xFFFFu) << 16);
            const float l3 = u_[3] - bitsf(uh23 & 0xFFFF0000u);
            *(uint4*)&sm.lp.uallp[t][s][0] =
                make_uint4(uh01, uh23, pack_rne(l0, l1), pack_rne(l2, l3));
        }
    }

    // gate scales: r/z sigmoid(x)=rcp(1+exp2(-log2e*x)); n tanh via +2log2e
    const float gsc[3] = { -LOG2E, -LOG2E, 2.0f * LOG2E };

    // ---- Whh A-fragments (prescaled): gate g3 x K-chunk c; idx = 2*g3+c ----
    Frag ahi[6], alo[6];
    #pragma unroll
    for (int g3 = 0; g3 < 3; ++g3){
        #pragma unroll
        for (int c = 0; c < 2; ++c){
            const int idx = g3 * 2 + c;
            const float* wp = Whh + (64 * g3 + 16 * w + sq) * 64 + 32 * c + 8 * q;
            const float4 fA = *(const float4*)wp;
            const float4 fB = *(const float4*)(wp + 4);
            const float s3 = gsc[g3];
            const float f[8] = {fA.x*s3, fA.y*s3, fA.z*s3, fA.w*s3,
                                fB.x*s3, fB.y*s3, fB.z*s3, fB.w*s3};
            #pragma unroll
            for (int p = 0; p < 4; ++p){
                const u32 hi = pack_rne(f[2*p], f[2*p+1]);
                ahi[idx].u[p] = hi;
                const float l0 = f[2*p]   - bitsf((hi & 0xFFFFu) << 16);
                const float l1 = f[2*p+1] - bitsf(hi & 0xFFFF0000u);
                alo[idx].u[p] = pack_rne(l0, l1);
            }
        }
    }

    // ---- Wih A-fragments (prescaled, hi/lo folded along K) ----
    // A[sq][k]: k0..3 = whi, k4..7 = wlo, k8..11 = whi, rest 0.
    Frag auR, auZ, auN;
    {
        Frag* dst[3] = { &auR, &auZ, &auN };
        #pragma unroll
        for (int g3 = 0; g3 < 3; ++g3){
            const int row = 64 * g3 + 16 * w + sq;
            const float4 wv4 = *(const float4*)&Wih[row * 4];
            const float s3 = gsc[g3];
            const float v0 = wv4.x*s3, v1 = wv4.y*s3, v2 = wv4.z*s3, v3 = wv4.w*s3;
            const u32 whi01 = pack_rne(v0, v1);
            const u32 whi23 = pack_rne(v2, v3);
            const float r0 = v0 - bitsf((whi01 & 0xFFFFu) << 16);
            const float r1 = v1 - bitsf(whi01 & 0xFFFF0000u);
            const float r2 = v2 - bitsf((whi23 & 0xFFFFu) << 16);
            const float r3 = v3 - bitsf(whi23 & 0xFFFF0000u);
            const u32 wlo01 = pack_rne(r0, r1);
            const u32 wlo23 = pack_rne(r2, r3);
            dst[g3]->u[0] = (q <= 1) ? whi01 : 0u;
            dst[g3]->u[1] = (q <= 1) ? whi23 : 0u;
            dst[g3]->u[2] = (q == 0) ? wlo01 : 0u;
            dst[g3]->u[3] = (q == 0) ? wlo23 : 0u;
        }
    }

    // ---- per-lane bias C-vectors (prescaled) for rows j = 16w+4q+r ----
    f32x4 bR4, bZ4, bNh4, bNi4;
    #pragma unroll
    for (int r = 0; r < 4; ++r){
        const int j = 16 * w + 4 * q + r;
        bR4[r]  = -LOG2E * (bih[j]       + bhh[j]);
        bZ4[r]  = -LOG2E * (bih[64 + j]  + bhh[64 + j]);
        bNi4[r] = 2.0f * LOG2E * bih[128 + j];
        bNh4[r] = 2.0f * LOG2E * bhh[128 + j];
    }

    float hreg[4] = {0.f, 0.f, 0.f, 0.f};

    __syncthreads();   // staging + h init + uallp visible

    #define MFMA_(A,B,C) __builtin_amdgcn_mfma_f32_16x16x32_bf16(A, B, C, 0, 0, 0)

    // One GRU step, RB a literal. Verbatim round-5 body + setprio fences.
    #define STEP_BODY(T, RB) { \
        const short8 bh0 = *(const short8*)&sm.lp.hh[RB][sq][8 * q]; \
        const short8 bl0 = *(const short8*)&sm.lp.hl[RB][sq][8 * q]; \
        const short8 bh1 = *(const short8*)&sm.lp.hh[RB][sq][32 + 8 * q]; \
        const short8 bl1 = *(const short8*)&sm.lp.hl[RB][sq][32 + 8 * q]; \
        const uint4 uv = *(const uint4*)&sm.lp.uallp[(T)][sq][0]; \
        Frag bu; \
        bu.u[0] = (q == 0) ? uv.x : ((q == 1) ? uv.z : 0u); \
        bu.u[1] = (q == 0) ? uv.y : ((q == 1) ? uv.w : 0u); \
        bu.u[2] = (q == 0) ? uv.x : 0u; \
        bu.u[3] = (q == 0) ? uv.y : 0u; \
        __builtin_amdgcn_s_setprio(1); \
        f32x4 aR = MFMA_(auR.s, bu.s, bR4); \
        aR = MFMA_(ahi[0].s, bh0, aR); aR = MFMA_(ahi[0].s, bl0, aR); aR = MFMA_(alo[0].s, bh0, aR); \
        aR = MFMA_(ahi[1].s, bh1, aR); aR = MFMA_(ahi[1].s, bl1, aR); aR = MFMA_(alo[1].s, bh1, aR); \
        f32x4 aZ = MFMA_(auZ.s, bu.s, bZ4); \
        aZ = MFMA_(ahi[2].s, bh0, aZ); aZ = MFMA_(ahi[2].s, bl0, aZ); aZ = MFMA_(alo[2].s, bh0, aZ); \
        aZ = MFMA_(ahi[3].s, bh1, aZ); aZ = MFMA_(ahi[3].s, bl1, aZ); aZ = MFMA_(alo[3].s, bh1, aZ); \
        f32x4 aN = MFMA_(ahi[4].s, bh0, bNh4); \
        aN = MFMA_(ahi[4].s, bl0, aN); aN = MFMA_(alo[4].s, bh0, aN); \
        aN = MFMA_(ahi[5].s, bh1, aN); aN = MFMA_(ahi[5].s, bl1, aN); aN = MFMA_(alo[5].s, bh1, aN); \
        f32x4 gN = MFMA_(auN.s, bu.s, bNi4); \
        __builtin_amdgcn_s_setprio(0); \
        float hn4[4]; \
        _Pragma("unroll") \
        for (int r = 0; r < 4; ++r){ \
            const float rr   = __builtin_amdgcn_rcpf(1.0f + __builtin_amdgcn_exp2f(aR[r])); \
            const float zz   = __builtin_amdgcn_rcpf(1.0f + __builtin_amdgcn_exp2f(aZ[r])); \
            const float y    = fmaf(rr, aN[r], gN[r]); \
            const float cand = fmaf(-2.0f, \
                __builtin_amdgcn_rcpf(__builtin_amdgcn_exp2f(y) + 1.0f), 1.0f); \
            const float hn   = fmaf(zz, hreg[r] - cand, cand); \
            hreg[r] = hn; \
            hn4[r] = hn; \
        } \
        { \
            const u32 hi0 = pack_trunc(hn4[0], hn4[1]); \
            const u32 hi1 = pack_trunc(hn4[2], hn4[3]); \
            const float l0 = hn4[0] - bitsf((hi0 & 0xFFFFu) << 16); \
            const float l1 = hn4[1] - bitsf(hi0 & 0xFFFF0000u); \
            const float l2 = hn4[2] - bitsf((hi1 & 0xFFFFu) << 16); \
            const float l3 = hn4[3] - bitsf(hi1 & 0xFFFF0000u); \
            const u32 lo0 = pack_trunc(l0, l1); \
            const u32 lo1 = pack_trunc(l2, l3); \
            *(uint2*)&sm.lp.hh[(RB)^1][sq][16 * w + 4 * q] = make_uint2(hi0, hi1); \
            *(uint2*)&sm.lp.hl[(RB)^1][sq][16 * w + 4 * q] = make_uint2(lo0, lo1); \
        } \
        __syncthreads(); \
    }

    #pragma unroll 1
    for (int tt = 0; tt < 32; ++tt){
        STEP_BODY(2*tt,     0)
        STEP_BODY(2*tt + 1, 1)
    }
    #undef STEP_BODY
    #undef MFMA_

    // ---- final h (f32) for the tail, straight from registers ----
    {
        const float4 hv = make_float4(hreg[0], hreg[1], hreg[2], hreg[3]);
        *(float4*)&sm.h[sq * 68 + 16 * w + 4 * q] = hv;
    }

    // ---- stage tail weights into the (dead) loop region ----
    for (int i = tid; i < 1152; i += 256) sm.tl.wl[i]  = Wl[i];
    for (int i = tid; i <  640; i += 256) sm.tl.wcf[i] = Wcf[i];
    for (int i = tid; i <  400; i += 256) sm.tl.wcm[i] = Wcm[i];
    if (tid < 80) sm.tl.wcc[tid] = Wcc[tid];
    if (tid < 20){
        sm.tl.bcf[tid]  = bcf[tid];
        sm.tl.bcc[tid]  = bcc[tid];
        sm.tl.bcm[tid]  = bcm[tid];
        sm.tl.wfin[tid] = Wfin[tid];
    }
    if (tid < 16) sm.tl.bl[tid] = bl[tid];
    if (tid == 0) sm.tl.bfin = bfin[0];
    __syncthreads();   // h writes + tail weights visible

    // ---- tail Phase A: wave (g = w&1) x (half = w>>1); 8 outputs/wave ----
    {
        const int g    = w & 1;
        const int half = w >> 1;
        const int b    = b_base + g;
        const int l = lane >> 3, o = lane & 7;
        float fv[8];
        const float vraw = feat[b * 16 + 8 + l];
        const int   bit  = ((int)feat[b * 16 + l]) & 1;
        #pragma unroll
        for (int c = 0; c < 4; ++c){
            fv[c]     = sigmoidf_(fmaf(vraw, Wv[c], bv[c]));
            fv[4 + c] = sigmoidf_(emb_phase[bit * 4 + c]);
        }
        const float* hrow = &sm.h[(g * 8 + l) * 68];
        const int oo = o + half * 8;
        float acc = sm.tl.bl[oo];
        #pragma unroll
        for (int f = 0; f < 8; ++f) acc = fmaf(fv[f], sm.tl.wl[oo * 72 + f], acc);
        for (int k = 0; k < 64; ++k) acc = fmaf(hrow[k], sm.tl.wl[oo * 72 + 8 + k], acc);
        sm.tl.line[g][l * 16 + oo] = fmaxf(acc, 0.0f);
    }
    __syncthreads();   // line written by wave pairs {g, g+2}

    // ---- Phases B/C/out: waves 0,1 only (wave-private from here) ----
    if (w < 2){
        const int g = w;
        const int b = b_base + g;
        // Phase B
        {
            const int p = lane >> 3, o = lane & 7;
            const int l0 = (0x64204501u >> (p * 4)) & 15;
            const int l1 = (0x75316723u >> (p * 4)) & 15;
            sm.tl.pp[g][p * 16 + o]     = sm.tl.line[g][l0 * 16 + o]     + sm.tl.line[g][l1 * 16 + o];
            sm.tl.pp[g][p * 16 + o + 8] = sm.tl.line[g][l0 * 16 + o + 8] + sm.tl.line[g][l1 * 16 + o + 8];
        }
        __builtin_amdgcn_wave_barrier();
        // Phase C
        if (lane < 56){
            const int p  = lane / 7;
            const int qi = lane - p * 7;
            const int jl = qi + (qi >= p ? 1 : 0);
            float fmv[32];
            #pragma unroll
            for (int f = 0; f < 16; ++f){
                fmv[f]      = sm.tl.pp[g][p  * 16 + f];
                fmv[16 + f] = sm.tl.pp[g][jl * 16 + f];
            }
            const int rel = relation[p * 7 + qi] & 1;
            float ce[4];
            #pragma unroll
            for (int c = 0; c < 4; ++c) ce[c] = emb_const[rel * 4 + c];
            float m[20];
            for (int o = 0; o < 20; ++o){
                float xf = sm.tl.bcf[o];
                #pragma unroll
                for (int f = 0; f < 32; ++f) xf = fmaf(fmv[f], sm.tl.wcf[o * 32 + f], xf);
                float yc = sm.tl.bcc[o];
                #pragma unroll
                for (int c = 0; c < 4; ++c) yc = fmaf(ce[c], sm.tl.wcc[o * 4 + c], yc);
                m[o] = fmaxf(xf, 0.0f) * fmaxf(yc, 0.0f);
            }
            float fin = sm.tl.bfin;
            for (int o = 0; o < 20; ++o){
                float zz = sm.tl.bcm[o];
                #pragma unroll
                for (int c = 0; c < 20; ++c) zz = fmaf(m[c], sm.tl.wcm[o * 20 + c], zz);
                fin = fmaf(fmaxf(zz, 0.0f), sm.tl.wfin[o], fin);
            }
            sm.tl.line[g][lane] = fin;   // line dead after Phase B
        }
        __builtin_amdgcn_wave_barrier();
        if (lane < 8){
            float acc = 0.0f;
            #pragma unroll
            for (int qq = 0; qq < 7; ++qq) acc += sm.tl.line[g][lane * 7 + qq];
            out[b * 8 + lane] = acc;
        }
    }
}

extern "C" void kernel_launch(void* const* d_in, const int* in_sizes, int n_in,
                              void* d_out, int out_size, void* d_ws, size_t ws_size,
                              hipStream_t stream) {
    (void)n_in; (void)d_ws; (void)ws_size; (void)out_size;
    const float* feat      = (const float*)d_in[0];
    const float* hist      = (const float*)d_in[1];
    const int*   relation  = (const int*)d_in[2];
    const float* emb_phase = (const float*)d_in[3];
    const float* Wv        = (const float*)d_in[4];
    const float* bv        = (const float*)d_in[5];
    const float* Wh        = (const float*)d_in[6];
    const float* bh        = (const float*)d_in[7];
    const float* Wih       = (const float*)d_in[8];
    const float* Whh       = (const float*)d_in[9];
    const float* bih       = (const float*)d_in[10];
    const float* bhh       = (const float*)d_in[11];
    const float* Wl        = (const float*)d_in[12];
    const float* bl        = (const float*)d_in[13];
    const float* emb_const = (const float*)d_in[14];
    const float* Wcf       = (const float*)d_in[15];
    const float* bcf       = (const float*)d_in[16];
    const float* Wcc       = (const float*)d_in[17];
    const float* bcc       = (const float*)d_in[18];
    const float* Wcm       = (const float*)d_in[19];
    const float* bcm       = (const float*)d_in[20];
    const float* Wfin      = (const float*)d_in[21];
    const float* bfin      = (const float*)d_in[22];
    float* out = (float*)d_out;

    const int B = in_sizes[0] / 16;     // 2048
    const int nblocks = B / 2;          // 1024 blocks x 4 waves: row-split GRU
    FRAPRQ_fused_kernel<<<nblocks, 256, 0, stream>>>(
        feat, hist, relation, emb_phase, Wv, bv, Wh, bh, Wih, Whh, bih, bhh,
        Wl, bl, emb_const, Wcf, bcf, Wcc, bcc, Wcm, bcm, Wfin, bfin, out);
}

// Round 8
// 193.436 us; speedup vs baseline: 1.0582x; 1.0259x over previous
//
#include <hip/hip_runtime.h>

typedef unsigned short u16;
typedef unsigned int   u32;

typedef __attribute__((ext_vector_type(8))) short short8;   // 8 bf16 (4 VGPRs)
typedef __attribute__((ext_vector_type(4))) float f32x4;    // MFMA acc

union Frag { u32 u[4]; short8 s; };

__device__ __forceinline__ u32 fbits(float f){ union{float f;u32 u;}x; x.f=f; return x.u; }
__device__ __forceinline__ float bitsf(u32 u){ union{u32 u;float f;}x; x.u=u; return x.f; }
__device__ __forceinline__ u32 pack_trunc(float a, float b){
    return __builtin_amdgcn_perm(fbits(b), fbits(a), 0x07060302u);
}
__device__ __forceinline__ u32 bf16_rne(float a){
    u32 u = fbits(a); return (u + 0x7FFFu + ((u >> 16) & 1u)) >> 16;
}
__device__ __forceinline__ u32 pack_rne(float a, float b){
    return bf16_rne(a) | (bf16_rne(b) << 16);
}
__device__ __forceinline__ float sigmoidf_(float x){
    return __builtin_amdgcn_rcpf(1.0f + __expf(-x));
}

#define LOG2E 1.4426950408889634f

// Row-split GRU: 4 waves, wave w owns h rows 16w..16w+15, full K=64, no
// partial exchange. Round-8: SINGLE bf16 h (RNE) — the hi/lo h pair is
// dropped. Rationale: round-7 counters show VALUBusy+MfmaUtil ~90% (issue
// port saturated); only removing issued work helps. Whh keeps hi/lo
// compensation (weights near-fp32, no systematic drift); h quantization is
// zero-mean RNE noise (rel <= 2^-9) that random-walks. MFMA 21->15/step,
// ds_read 5->3, ds_write 2->1. Numerics risk pre-committed: absmax must
// stay < 7.93e-3 (expect ~3-6e-3); on fail, revert to round-7.
struct __align__(16) SharedMem {
    union {
        struct {                       // loop state: 20,992 B
            u16 hh[2][16][72];         // h bf16 (RNE), ping-pong [buf][seq][k]
            u32 uallp[64][16][4];      // packed u: {uh01,uh23,ul01,ul23} (16 KB)
        } lp;
        struct {                       // tail: 11,524 B
            float wl[1152];
            float bl[16];
            float wcf[640];
            float bcf[20];
            float wcc[80];
            float bcc[20];
            float wcm[400];
            float bcm[20];
            float wfin[20];
            float bfin;
            float line[2][128];
            float pp[2][128];
        } tl;
    };
    float h[16 * 68];                  // final h (f32) for the tail, 4352 B
};

__global__ __launch_bounds__(256, 4)
void FRAPRQ_fused_kernel(
    const float* __restrict__ feat,       // (B,16)
    const float* __restrict__ hist,       // (B,64,24)
    const int*   __restrict__ relation,   // (8,7)
    const float* __restrict__ emb_phase,  // (2,4)
    const float* __restrict__ Wv,         // (4,1)
    const float* __restrict__ bv,         // (4)
    const float* __restrict__ Wh,         // (4,3)
    const float* __restrict__ bh,         // (4)
    const float* __restrict__ Wih,        // (192,4)
    const float* __restrict__ Whh,        // (192,64)
    const float* __restrict__ bih,        // (192)
    const float* __restrict__ bhh,        // (192)
    const float* __restrict__ Wl,         // (16,72)
    const float* __restrict__ bl,         // (16)
    const float* __restrict__ emb_const,  // (2,4)
    const float* __restrict__ Wcf,        // (20,32)
    const float* __restrict__ bcf,        // (20)
    const float* __restrict__ Wcc,        // (20,4)
    const float* __restrict__ bcc,        // (20)
    const float* __restrict__ Wcm,        // (20,20)
    const float* __restrict__ bcm,        // (20)
    const float* __restrict__ Wfin,      // (1,20)
    const float* __restrict__ bfin,      // (1)
    float* __restrict__ out)             // (B,8)
{
    __shared__ SharedMem sm;
    const int tid  = threadIdx.x;        // 0..255
    const int w    = tid >> 6;           // wave 0..3: owns h rows 16w..16w+15
    const int lane = tid & 63;
    const int sq   = lane & 15;          // MFMA column: local seq (2 b's x 8 lanes)
    const int q    = lane >> 4;          // MFMA quad
    const int b_base = blockIdx.x * 2;

    // ---- cooperative staging ----
    {   // zero both h ping-pong buffers (h(-1) = 0): 1152 u32
        u32* z = (u32*)&sm.lp.hh[0][0][0];
        #pragma unroll 1
        for (int i = tid; i < 1152; i += 256) z[i] = 0u;
    }

    // ---- u precompute + bf16 hi/lo pack: thread = (seq s, t-group) ----
    {
        const int s  = tid & 15;         // seq
        const int tg = tid >> 4;         // 0..15 -> t = 4*tg + i
        const int bs_ = b_base + (s >> 3), ls_ = s & 7;
        const float* hbp = hist + (size_t)bs_ * 1536;
        float whc[12], bhc[4];
        #pragma unroll
        for (int c = 0; c < 4; ++c){
            whc[c*3+0] = Wh[c*3+0]; whc[c*3+1] = Wh[c*3+1]; whc[c*3+2] = Wh[c*3+2];
            bhc[c] = bh[c];
        }
        #pragma unroll
        for (int i = 0; i < 4; ++i){
            const int t = tg * 4 + i;
            const float x0 = hbp[t*24 + ls_];
            const float x1 = hbp[t*24 + ls_ + 8];
            const float x2 = hbp[t*24 + ls_ + 16];
            float u_[4];
            #pragma unroll
            for (int c = 0; c < 4; ++c)
                u_[c] = sigmoidf_(fmaf(whc[c*3], x0, fmaf(whc[c*3+1], x1, fmaf(whc[c*3+2], x2, bhc[c]))));
            const u32 uh01 = pack_rne(u_[0], u_[1]);
            const u32 uh23 = pack_rne(u_[2], u_[3]);
            const float l0 = u_[0] - bitsf((uh01 & 0xFFFFu) << 16);
            const float l1 = u_[1] - bitsf(uh01 & 0xFFFF0000u);
            const float l2 = u_[2] - bitsf((uh23 & 0xFFFFu) << 16);
            const float l3 = u_[3] - bitsf(uh23 & 0xFFFF0000u);
            *(uint4*)&sm.lp.uallp[t][s][0] =
                make_uint4(uh01, uh23, pack_rne(l0, l1), pack_rne(l2, l3));
        }
    }

    // gate scales: r/z sigmoid(x)=rcp(1+exp2(-log2e*x)); n tanh via +2log2e
    const float gsc[3] = { -LOG2E, -LOG2E, 2.0f * LOG2E };

    // ---- Whh A-fragments (prescaled): gate g3 x K-chunk c; idx = 2*g3+c ----
    Frag ahi[6], alo[6];
    #pragma unroll
    for (int g3 = 0; g3 < 3; ++g3){
        #pragma unroll
        for (int c = 0; c < 2; ++c){
            const int idx = g3 * 2 + c;
            const float* wp = Whh + (64 * g3 + 16 * w + sq) * 64 + 32 * c + 8 * q;
            const float4 fA = *(const float4*)wp;
            const float4 fB = *(const float4*)(wp + 4);
            const float s3 = gsc[g3];
            const float f[8] = {fA.x*s3, fA.y*s3, fA.z*s3, fA.w*s3,
                                fB.x*s3, fB.y*s3, fB.z*s3, fB.w*s3};
            #pragma unroll
            for (int p = 0; p < 4; ++p){
                const u32 hi = pack_rne(f[2*p], f[2*p+1]);
                ahi[idx].u[p] = hi;
                const float l0 = f[2*p]   - bitsf((hi & 0xFFFFu) << 16);
                const float l1 = f[2*p+1] - bitsf(hi & 0xFFFF0000u);
                alo[idx].u[p] = pack_rne(l0, l1);
            }
        }
    }

    // ---- Wih A-fragments (prescaled, hi/lo folded along K) ----
    // A[sq][k]: k0..3 = whi, k4..7 = wlo, k8..11 = whi, rest 0.
    Frag auR, auZ, auN;
    {
        Frag* dst[3] = { &auR, &auZ, &auN };
        #pragma unroll
        for (int g3 = 0; g3 < 3; ++g3){
            const int row = 64 * g3 + 16 * w + sq;
            const float4 wv4 = *(const float4*)&Wih[row * 4];
            const float s3 = gsc[g3];
            const float v0 = wv4.x*s3, v1 = wv4.y*s3, v2 = wv4.z*s3, v3 = wv4.w*s3;
            const u32 whi01 = pack_rne(v0, v1);
            const u32 whi23 = pack_rne(v2, v3);
            const float r0 = v0 - bitsf((whi01 & 0xFFFFu) << 16);
            const float r1 = v1 - bitsf(whi01 & 0xFFFF0000u);
            const float r2 = v2 - bitsf((whi23 & 0xFFFFu) << 16);
            const float r3 = v3 - bitsf(whi23 & 0xFFFF0000u);
            const u32 wlo01 = pack_rne(r0, r1);
            const u32 wlo23 = pack_rne(r2, r3);
            dst[g3]->u[0] = (q <= 1) ? whi01 : 0u;
            dst[g3]->u[1] = (q <= 1) ? whi23 : 0u;
            dst[g3]->u[2] = (q == 0) ? wlo01 : 0u;
            dst[g3]->u[3] = (q == 0) ? wlo23 : 0u;
        }
    }

    // ---- per-lane bias C-vectors (prescaled) for rows j = 16w+4q+r ----
    f32x4 bR4, bZ4, bNh4, bNi4;
    #pragma unroll
    for (int r = 0; r < 4; ++r){
        const int j = 16 * w + 4 * q + r;
        bR4[r]  = -LOG2E * (bih[j]       + bhh[j]);
        bZ4[r]  = -LOG2E * (bih[64 + j]  + bhh[64 + j]);
        bNi4[r] = 2.0f * LOG2E * bih[128 + j];
        bNh4[r] = 2.0f * LOG2E * bhh[128 + j];
    }

    float hreg[4] = {0.f, 0.f, 0.f, 0.f};

    __syncthreads();   // staging + h init + uallp visible

    #define MFMA_(A,B,C) __builtin_amdgcn_mfma_f32_16x16x32_bf16(A, B, C, 0, 0, 0)

    // One GRU step, RB a literal. 15 MFMAs: W hi/lo comp, h single-bf16.
    #define STEP_BODY(T, RB) { \
        const short8 bh0 = *(const short8*)&sm.lp.hh[RB][sq][8 * q]; \
        const short8 bh1 = *(const short8*)&sm.lp.hh[RB][sq][32 + 8 * q]; \
        const uint4 uv = *(const uint4*)&sm.lp.uallp[(T)][sq][0]; \
        Frag bu; \
        bu.u[0] = (q == 0) ? uv.x : ((q == 1) ? uv.z : 0u); \
        bu.u[1] = (q == 0) ? uv.y : ((q == 1) ? uv.w : 0u); \
        bu.u[2] = (q == 0) ? uv.x : 0u; \
        bu.u[3] = (q == 0) ? uv.y : 0u; \
        __builtin_amdgcn_s_setprio(1); \
        f32x4 aR = MFMA_(auR.s, bu.s, bR4); \
        aR = MFMA_(ahi[0].s, bh0, aR); aR = MFMA_(alo[0].s, bh0, aR); \
        aR = MFMA_(ahi[1].s, bh1, aR); aR = MFMA_(alo[1].s, bh1, aR); \
        f32x4 aZ = MFMA_(auZ.s, bu.s, bZ4); \
        aZ = MFMA_(ahi[2].s, bh0, aZ); aZ = MFMA_(alo[2].s, bh0, aZ); \
        aZ = MFMA_(ahi[3].s, bh1, aZ); aZ = MFMA_(alo[3].s, bh1, aZ); \
        f32x4 aN = MFMA_(ahi[4].s, bh0, bNh4); \
        aN = MFMA_(alo[4].s, bh0, aN); \
        aN = MFMA_(ahi[5].s, bh1, aN); aN = MFMA_(alo[5].s, bh1, aN); \
        f32x4 gN = MFMA_(auN.s, bu.s, bNi4); \
        __builtin_amdgcn_s_setprio(0); \
        float hn4[4]; \
        _Pragma("unroll") \
        for (int r = 0; r < 4; ++r){ \
            const float rr   = __builtin_amdgcn_rcpf(1.0f + __builtin_amdgcn_exp2f(aR[r])); \
            const float zz   = __builtin_amdgcn_rcpf(1.0f + __builtin_amdgcn_exp2f(aZ[r])); \
            const float y    = fmaf(rr, aN[r], gN[r]); \
            const float cand = fmaf(-2.0f, \
                __builtin_amdgcn_rcpf(__builtin_amdgcn_exp2f(y) + 1.0f), 1.0f); \
            const float hn   = fmaf(zz, hreg[r] - cand, cand); \
            hreg[r] = hn; \
            hn4[r] = hn; \
        } \
        { \
            const u32 hi0 = pack_rne(hn4[0], hn4[1]); \
            const u32 hi1 = pack_rne(hn4[2], hn4[3]); \
            *(uint2*)&sm.lp.hh[(RB)^1][sq][16 * w + 4 * q] = make_uint2(hi0, hi1); \
        } \
        __syncthreads(); \
    }

    #pragma unroll 1
    for (int tt = 0; tt < 32; ++tt){
        STEP_BODY(2*tt,     0)
        STEP_BODY(2*tt + 1, 1)
    }
    #undef STEP_BODY
    #undef MFMA_

    // ---- final h (f32) for the tail, straight from registers ----
    {
        const float4 hv = make_float4(hreg[0], hreg[1], hreg[2], hreg[3]);
        *(float4*)&sm.h[sq * 68 + 16 * w + 4 * q] = hv;
    }

    // ---- stage tail weights into the (dead) loop region ----
    for (int i = tid; i < 1152; i += 256) sm.tl.wl[i]  = Wl[i];
    for (int i = tid; i <  640; i += 256) sm.tl.wcf[i] = Wcf[i];
    for (int i = tid; i <  400; i += 256) sm.tl.wcm[i] = Wcm[i];
    if (tid < 80) sm.tl.wcc[tid] = Wcc[tid];
    if (tid < 20){
        sm.tl.bcf[tid]  = bcf[tid];
        sm.tl.bcc[tid]  = bcc[tid];
        sm.tl.bcm[tid]  = bcm[tid];
        sm.tl.wfin[tid] = Wfin[tid];
    }
    if (tid < 16) sm.tl.bl[tid] = bl[tid];
    if (tid == 0) sm.tl.bfin = bfin[0];
    __syncthreads();   // h writes + tail weights visible

    // ---- tail Phase A: wave (g = w&1) x (half = w>>1); 8 outputs/wave ----
    {
        const int g    = w & 1;
        const int half = w >> 1;
        const int b    = b_base + g;
        const int l = lane >> 3, o = lane & 7;
        float fv[8];
        const float vraw = feat[b * 16 + 8 + l];
        const int   bit  = ((int)feat[b * 16 + l]) & 1;
        #pragma unroll
        for (int c = 0; c < 4; ++c){
            fv[c]     = sigmoidf_(fmaf(vraw, Wv[c], bv[c]));
            fv[4 + c] = sigmoidf_(emb_phase[bit * 4 + c]);
        }
        const float* hrow = &sm.h[(g * 8 + l) * 68];
        const int oo = o + half * 8;
        float acc = sm.tl.bl[oo];
        #pragma unroll
        for (int f = 0; f < 8; ++f) acc = fmaf(fv[f], sm.tl.wl[oo * 72 + f], acc);
        for (int k = 0; k < 64; ++k) acc = fmaf(hrow[k], sm.tl.wl[oo * 72 + 8 + k], acc);
        sm.tl.line[g][l * 16 + oo] = fmaxf(acc, 0.0f);
    }
    __syncthreads();   // line written by wave pairs {g, g+2}

    // ---- Phases B/C/out: waves 0,1 only (wave-private from here) ----
    if (w < 2){
        const int g = w;
        const int b = b_base + g;
        // Phase B
        {
            const int p = lane >> 3, o = lane & 7;
            const int l0 = (0x64204501u >> (p * 4)) & 15;
            const int l1 = (0x75316723u >> (p * 4)) & 15;
            sm.tl.pp[g][p * 16 + o]     = sm.tl.line[g][l0 * 16 + o]     + sm.tl.line[g][l1 * 16 + o];
            sm.tl.pp[g][p * 16 + o + 8] = sm.tl.line[g][l0 * 16 + o + 8] + sm.tl.line[g][l1 * 16 + o + 8];
        }
        __builtin_amdgcn_wave_barrier();
        // Phase C
        if (lane < 56){
            const int p  = lane / 7;
            const int qi = lane - p * 7;
            const int jl = qi + (qi >= p ? 1 : 0);
            float fmv[32];
            #pragma unroll
            for (int f = 0; f < 16; ++f){
                fmv[f]      = sm.tl.pp[g][p  * 16 + f];
                fmv[16 + f] = sm.tl.pp[g][jl * 16 + f];
            }
            const int rel = relation[p * 7 + qi] & 1;
            float ce[4];
            #pragma unroll
            for (int c = 0; c < 4; ++c) ce[c] = emb_const[rel * 4 + c];
            float m[20];
            for (int o = 0; o < 20; ++o){
                float xf = sm.tl.bcf[o];
                #pragma unroll
                for (int f = 0; f < 32; ++f) xf = fmaf(fmv[f], sm.tl.wcf[o * 32 + f], xf);
                float yc = sm.tl.bcc[o];
                #pragma unroll
                for (int c = 0; c < 4; ++c) yc = fmaf(ce[c], sm.tl.wcc[o * 4 + c], yc);
                m[o] = fmaxf(xf, 0.0f) * fmaxf(yc, 0.0f);
            }
            float fin = sm.tl.bfin;
            for (int o = 0; o < 20; ++o){
                float zz = sm.tl.bcm[o];
                #pragma unroll
                for (int c = 0; c < 20; ++c) zz = fmaf(m[c], sm.tl.wcm[o * 20 + c], zz);
                fin = fmaf(fmaxf(zz, 0.0f), sm.tl.wfin[o], fin);
            }
            sm.tl.line[g][lane] = fin;   // line dead after Phase B
        }
        __builtin_amdgcn_wave_barrier();
        if (lane < 8){
            float acc = 0.0f;
            #pragma unroll
            for (int qq = 0; qq < 7; ++qq) acc += sm.tl.line[g][lane * 7 + qq];
            out[b * 8 + lane] = acc;
        }
    }
}

extern "C" void kernel_launch(void* const* d_in, const int* in_sizes, int n_in,
                              void* d_out, int out_size, void* d_ws, size_t ws_size,
                              hipStream_t stream) {
    (void)n_in; (void)d_ws; (void)ws_size; (void)out_size;
    const float* feat      = (const float*)d_in[0];
    const float* hist      = (const float*)d_in[1];
    const int*   relation  = (const int*)d_in[2];
    const float* emb_phase = (const float*)d_in[3];
    const float* Wv        = (const float*)d_in[4];
    const float* bv        = (const float*)d_in[5];
    const float* Wh        = (const float*)d_in[6];
    const float* bh        = (const float*)d_in[7];
    const float* Wih       = (const float*)d_in[8];
    const float* Whh       = (const float*)d_in[9];
    const float* bih       = (const float*)d_in[10];
    const float* bhh       = (const float*)d_in[11];
    const float* Wl        = (const float*)d_in[12];
    const float* bl        = (const float*)d_in[13];
    const float* emb_const = (const float*)d_in[14];
    const float* Wcf       = (const float*)d_in[15];
    const float* bcf       = (const float*)d_in[16];
    const float* Wcc       = (const float*)d_in[17];
    const float* bcc       = (const float*)d_in[18];
    const float* Wcm       = (const float*)d_in[19];
    const float* bcm       = (const float*)d_in[20];
    const float* Wfin      = (const float*)d_in[21];
    const float* bfin      = (const float*)d_in[22];
    float* out = (float*)d_out;

    const int B = in_sizes[0] / 16;     // 2048
    const int nblocks = B / 2;          // 1024 blocks x 4 waves: row-split GRU
    FRAPRQ_fused_kernel<<<nblocks, 256, 0, stream>>>(
        feat, hist, relation, emb_phase, Wv, bv, Wh, bh, Wih, Whh, bih, bhh,
        Wl, bl, emb_const, Wcf, bcf, Wcc, bcc, Wcm, bcm, Wfin, bfin, out);
}

// Round 9
// 185.915 us; speedup vs baseline: 1.1011x; 1.0405x over previous
//
#include <hip/hip_runtime.h>

typedef unsigned short u16;
typedef unsigned int   u32;

typedef __attribute__((ext_vector_type(8))) short short8;   // 8 bf16 (4 VGPRs)
typedef __attribute__((ext_vector_type(4))) float f32x4;    // MFMA acc

union Frag { u32 u[4]; short8 s; };

__device__ __forceinline__ u32 fbits(float f){ union{float f;u32 u;}x; x.f=f; return x.u; }
__device__ __forceinline__ float bitsf(u32 u){ union{u32 u;float f;}x; x.u=u; return x.f; }
// HW packed f32->bf16 (RNE on gfx950): D = {lo16: cvt(a), hi16: cvt(b)}.
// Replaces the ~10-op integer RNE pack (compiler does not fuse the hand-rolled
// form — round-8 asm had zero v_cvt in the loop).
__device__ __forceinline__ u32 cvt_pk_bf16(float a, float b){
    u32 r;
    asm("v_cvt_pk_bf16_f32 %0, %1, %2" : "=v"(r) : "v"(a), "v"(b));
    return r;
}
__device__ __forceinline__ float sigmoidf_(float x){
    return __builtin_amdgcn_rcpf(1.0f + __expf(-x));
}

#define LOG2E 1.4426950408889634f

// Row-split GRU: 4 waves, wave w owns h rows 16w..16w+15, full K=64, no
// partial exchange. Single bf16 h (RNE) in ping-pong LDS (round 8); Whh/Wih
// keep hi/lo compensation; exp2-prescaled gates. Round-9 (VALU-shrink only,
// protocol unchanged):
//  - v_cvt_pk_bf16_f32 replaces all hand-rolled RNE packs (loop -18
//    instr/step, preamble ~-900 instrs)
//  - uallp read for t+1 software-pipelined across the barrier (read-only
//    data; hides LDS latency at the gi-chain head)
// Numerics expected bit-identical to round 8 (canary 0.001953125).
struct __align__(16) SharedMem {
    union {
        struct {                       // loop state: 20,992 B
            u16 hh[2][16][72];         // h bf16 (RNE), ping-pong [buf][seq][k]
            u32 uallp[64][16][4];      // packed u: {uh01,uh23,ul01,ul23} (16 KB)
        } lp;
        struct {                       // tail: 11,524 B
            float wl[1152];
            float bl[16];
            float wcf[640];
            float bcf[20];
            float wcc[80];
            float bcc[20];
            float wcm[400];
            float bcm[20];
            float wfin[20];
            float bfin;
            float line[2][128];
            float pp[2][128];
        } tl;
    };
    float h[16 * 68];                  // final h (f32) for the tail, 4352 B
};

__global__ __launch_bounds__(256, 4)
void FRAPRQ_fused_kernel(
    const float* __restrict__ feat,       // (B,16)
    const float* __restrict__ hist,       // (B,64,24)
    const int*   __restrict__ relation,   // (8,7)
    const float* __restrict__ emb_phase,  // (2,4)
    const float* __restrict__ Wv,         // (4,1)
    const float* __restrict__ bv,         // (4)
    const float* __restrict__ Wh,         // (4,3)
    const float* __restrict__ bh,         // (4)
    const float* __restrict__ Wih,        // (192,4)
    const float* __restrict__ Whh,        // (192,64)
    const float* __restrict__ bih,        // (192)
    const float* __restrict__ bhh,        // (192)
    const float* __restrict__ Wl,         // (16,72)
    const float* __restrict__ bl,         // (16)
    const float* __restrict__ emb_const,  // (2,4)
    const float* __restrict__ Wcf,        // (20,32)
    const float* __restrict__ bcf,        // (20)
    const float* __restrict__ Wcc,        // (20,4)
    const float* __restrict__ bcc,        // (20)
    const float* __restrict__ Wcm,        // (20,20)
    const float* __restrict__ bcm,        // (20)
    const float* __restrict__ Wfin,      // (1,20)
    const float* __restrict__ bfin,      // (1)
    float* __restrict__ out)             // (B,8)
{
    __shared__ SharedMem sm;
    const int tid  = threadIdx.x;        // 0..255
    const int w    = tid >> 6;           // wave 0..3: owns h rows 16w..16w+15
    const int lane = tid & 63;
    const int sq   = lane & 15;          // MFMA column: local seq (2 b's x 8 lanes)
    const int q    = lane >> 4;          // MFMA quad
    const int b_base = blockIdx.x * 2;

    // ---- cooperative staging ----
    {   // zero both h ping-pong buffers (h(-1) = 0): 1152 u32
        u32* z = (u32*)&sm.lp.hh[0][0][0];
        #pragma unroll 1
        for (int i = tid; i < 1152; i += 256) z[i] = 0u;
    }

    // ---- u precompute + bf16 hi/lo pack: thread = (seq s, t-group) ----
    {
        const int s  = tid & 15;         // seq
        const int tg = tid >> 4;         // 0..15 -> t = 4*tg + i
        const int bs_ = b_base + (s >> 3), ls_ = s & 7;
        const float* hbp = hist + (size_t)bs_ * 1536;
        float whc[12], bhc[4];
        #pragma unroll
        for (int c = 0; c < 4; ++c){
            whc[c*3+0] = Wh[c*3+0]; whc[c*3+1] = Wh[c*3+1]; whc[c*3+2] = Wh[c*3+2];
            bhc[c] = bh[c];
        }
        #pragma unroll
        for (int i = 0; i < 4; ++i){
            const int t = tg * 4 + i;
            const float x0 = hbp[t*24 + ls_];
            const float x1 = hbp[t*24 + ls_ + 8];
            const float x2 = hbp[t*24 + ls_ + 16];
            float u_[4];
            #pragma unroll
            for (int c = 0; c < 4; ++c)
                u_[c] = sigmoidf_(fmaf(whc[c*3], x0, fmaf(whc[c*3+1], x1, fmaf(whc[c*3+2], x2, bhc[c]))));
            const u32 uh01 = cvt_pk_bf16(u_[0], u_[1]);
            const u32 uh23 = cvt_pk_bf16(u_[2], u_[3]);
            const float l0 = u_[0] - bitsf((uh01 & 0xFFFFu) << 16);
            const float l1 = u_[1] - bitsf(uh01 & 0xFFFF0000u);
            const float l2 = u_[2] - bitsf((uh23 & 0xFFFFu) << 16);
            const float l3 = u_[3] - bitsf(uh23 & 0xFFFF0000u);
            *(uint4*)&sm.lp.uallp[t][s][0] =
                make_uint4(uh01, uh23, cvt_pk_bf16(l0, l1), cvt_pk_bf16(l2, l3));
        }
    }

    // gate scales: r/z sigmoid(x)=rcp(1+exp2(-log2e*x)); n tanh via +2log2e
    const float gsc[3] = { -LOG2E, -LOG2E, 2.0f * LOG2E };

    // ---- Whh A-fragments (prescaled): gate g3 x K-chunk c; idx = 2*g3+c ----
    Frag ahi[6], alo[6];
    #pragma unroll
    for (int g3 = 0; g3 < 3; ++g3){
        #pragma unroll
        for (int c = 0; c < 2; ++c){
            const int idx = g3 * 2 + c;
            const float* wp = Whh + (64 * g3 + 16 * w + sq) * 64 + 32 * c + 8 * q;
            const float4 fA = *(const float4*)wp;
            const float4 fB = *(const float4*)(wp + 4);
            const float s3 = gsc[g3];
            const float f[8] = {fA.x*s3, fA.y*s3, fA.z*s3, fA.w*s3,
                                fB.x*s3, fB.y*s3, fB.z*s3, fB.w*s3};
            #pragma unroll
            for (int p = 0; p < 4; ++p){
                const u32 hi = cvt_pk_bf16(f[2*p], f[2*p+1]);
                ahi[idx].u[p] = hi;
                const float l0 = f[2*p]   - bitsf((hi & 0xFFFFu) << 16);
                const float l1 = f[2*p+1] - bitsf(hi & 0xFFFF0000u);
                alo[idx].u[p] = cvt_pk_bf16(l0, l1);
            }
        }
    }

    // ---- Wih A-fragments (prescaled, hi/lo folded along K) ----
    // A[sq][k]: k0..3 = whi, k4..7 = wlo, k8..11 = whi, rest 0.
    Frag auR, auZ, auN;
    {
        Frag* dst[3] = { &auR, &auZ, &auN };
        #pragma unroll
        for (int g3 = 0; g3 < 3; ++g3){
            const int row = 64 * g3 + 16 * w + sq;
            const float4 wv4 = *(const float4*)&Wih[row * 4];
            const float s3 = gsc[g3];
            const float v0 = wv4.x*s3, v1 = wv4.y*s3, v2 = wv4.z*s3, v3 = wv4.w*s3;
            const u32 whi01 = cvt_pk_bf16(v0, v1);
            const u32 whi23 = cvt_pk_bf16(v2, v3);
            const float r0 = v0 - bitsf((whi01 & 0xFFFFu) << 16);
            const float r1 = v1 - bitsf(whi01 & 0xFFFF0000u);
            const float r2 = v2 - bitsf((whi23 & 0xFFFFu) << 16);
            const float r3 = v3 - bitsf(whi23 & 0xFFFF0000u);
            const u32 wlo01 = cvt_pk_bf16(r0, r1);
            const u32 wlo23 = cvt_pk_bf16(r2, r3);
            dst[g3]->u[0] = (q <= 1) ? whi01 : 0u;
            dst[g3]->u[1] = (q <= 1) ? whi23 : 0u;
            dst[g3]->u[2] = (q == 0) ? wlo01 : 0u;
            dst[g3]->u[3] = (q == 0) ? wlo23 : 0u;
        }
    }

    // ---- per-lane bias C-vectors (prescaled) for rows j = 16w+4q+r ----
    f32x4 bR4, bZ4, bNh4, bNi4;
    #pragma unroll
    for (int r = 0; r < 4; ++r){
        const int j = 16 * w + 4 * q + r;
        bR4[r]  = -LOG2E * (bih[j]       + bhh[j]);
        bZ4[r]  = -LOG2E * (bih[64 + j]  + bhh[64 + j]);
        bNi4[r] = 2.0f * LOG2E * bih[128 + j];
        bNh4[r] = 2.0f * LOG2E * bhh[128 + j];
    }

    float hreg[4] = {0.f, 0.f, 0.f, 0.f};

    __syncthreads();   // staging + h init + uallp visible

    #define MFMA_(A,B,C) __builtin_amdgcn_mfma_f32_16x16x32_bf16(A, B, C, 0, 0, 0)

    // One GRU step, RB a literal. UVC = this step's u (pre-loaded); UVN is
    // loaded HERE (before the barrier) for the next step — uallp is
    // read-only, so the prefetch crosses the barrier safely.
    #define STEP_BODY(T, RB, UVC, UVN) { \
        const short8 bh0 = *(const short8*)&sm.lp.hh[RB][sq][8 * q]; \
        const short8 bh1 = *(const short8*)&sm.lp.hh[RB][sq][32 + 8 * q]; \
        { const int tn = ((T) < 63) ? (T) + 1 : 63; \
          UVN = *(const uint4*)&sm.lp.uallp[tn][sq][0]; } \
        Frag bu; \
        bu.u[0] = (q == 0) ? UVC.x : ((q == 1) ? UVC.z : 0u); \
        bu.u[1] = (q == 0) ? UVC.y : ((q == 1) ? UVC.w : 0u); \
        bu.u[2] = (q == 0) ? UVC.x : 0u; \
        bu.u[3] = (q == 0) ? UVC.y : 0u; \
        __builtin_amdgcn_s_setprio(1); \
        f32x4 aR = MFMA_(auR.s, bu.s, bR4); \
        aR = MFMA_(ahi[0].s, bh0, aR); aR = MFMA_(alo[0].s, bh0, aR); \
        aR = MFMA_(ahi[1].s, bh1, aR); aR = MFMA_(alo[1].s, bh1, aR); \
        f32x4 aZ = MFMA_(auZ.s, bu.s, bZ4); \
        aZ = MFMA_(ahi[2].s, bh0, aZ); aZ = MFMA_(alo[2].s, bh0, aZ); \
        aZ = MFMA_(ahi[3].s, bh1, aZ); aZ = MFMA_(alo[3].s, bh1, aZ); \
        f32x4 aN = MFMA_(ahi[4].s, bh0, bNh4); \
        aN = MFMA_(alo[4].s, bh0, aN); \
        aN = MFMA_(ahi[5].s, bh1, aN); aN = MFMA_(alo[5].s, bh1, aN); \
        f32x4 gN = MFMA_(auN.s, bu.s, bNi4); \
        __builtin_amdgcn_s_setprio(0); \
        float hn4[4]; \
        _Pragma("unroll") \
        for (int r = 0; r < 4; ++r){ \
            const float rr   = __builtin_amdgcn_rcpf(1.0f + __builtin_amdgcn_exp2f(aR[r])); \
            const float zz   = __builtin_amdgcn_rcpf(1.0f + __builtin_amdgcn_exp2f(aZ[r])); \
            const float y    = fmaf(rr, aN[r], gN[r]); \
            const float cand = fmaf(-2.0f, \
                __builtin_amdgcn_rcpf(__builtin_amdgcn_exp2f(y) + 1.0f), 1.0f); \
            const float hn   = fmaf(zz, hreg[r] - cand, cand); \
            hreg[r] = hn; \
            hn4[r] = hn; \
        } \
        { \
            const u32 hi0 = cvt_pk_bf16(hn4[0], hn4[1]); \
            const u32 hi1 = cvt_pk_bf16(hn4[2], hn4[3]); \
            *(uint2*)&sm.lp.hh[(RB)^1][sq][16 * w + 4 * q] = make_uint2(hi0, hi1); \
        } \
        __syncthreads(); \
    }

    uint4 uvA = *(const uint4*)&sm.lp.uallp[0][sq][0];
    uint4 uvB;
    #pragma unroll 1
    for (int tt = 0; tt < 32; ++tt){
        STEP_BODY(2*tt,     0, uvA, uvB)
        STEP_BODY(2*tt + 1, 1, uvB, uvA)
    }
    #undef STEP_BODY
    #undef MFMA_

    // ---- final h (f32) for the tail, straight from registers ----
    {
        const float4 hv = make_float4(hreg[0], hreg[1], hreg[2], hreg[3]);
        *(float4*)&sm.h[sq * 68 + 16 * w + 4 * q] = hv;
    }

    // ---- stage tail weights into the (dead) loop region ----
    for (int i = tid; i < 1152; i += 256) sm.tl.wl[i]  = Wl[i];
    for (int i = tid; i <  640; i += 256) sm.tl.wcf[i] = Wcf[i];
    for (int i = tid; i <  400; i += 256) sm.tl.wcm[i] = Wcm[i];
    if (tid < 80) sm.tl.wcc[tid] = Wcc[tid];
    if (tid < 20){
        sm.tl.bcf[tid]  = bcf[tid];
        sm.tl.bcc[tid]  = bcc[tid];
        sm.tl.bcm[tid]  = bcm[tid];
        sm.tl.wfin[tid] = Wfin[tid];
    }
    if (tid < 16) sm.tl.bl[tid] = bl[tid];
    if (tid == 0) sm.tl.bfin = bfin[0];
    __syncthreads();   // h writes + tail weights visible

    // ---- tail Phase A: wave (g = w&1) x (half = w>>1); 8 outputs/wave ----
    {
        const int g    = w & 1;
        const int half = w >> 1;
        const int b    = b_base + g;
        const int l = lane >> 3, o = lane & 7;
        float fv[8];
        const float vraw = feat[b * 16 + 8 + l];
        const int   bit  = ((int)feat[b * 16 + l]) & 1;
        #pragma unroll
        for (int c = 0; c < 4; ++c){
            fv[c]     = sigmoidf_(fmaf(vraw, Wv[c], bv[c]));
            fv[4 + c] = sigmoidf_(emb_phase[bit * 4 + c]);
        }
        const float* hrow = &sm.h[(g * 8 + l) * 68];
        const int oo = o + half * 8;
        float acc = sm.tl.bl[oo];
        #pragma unroll
        for (int f = 0; f < 8; ++f) acc = fmaf(fv[f], sm.tl.wl[oo * 72 + f], acc);
        for (int k = 0; k < 64; ++k) acc = fmaf(hrow[k], sm.tl.wl[oo * 72 + 8 + k], acc);
        sm.tl.line[g][l * 16 + oo] = fmaxf(acc, 0.0f);
    }
    __syncthreads();   // line written by wave pairs {g, g+2}

    // ---- Phases B/C/out: waves 0,1 only (wave-private from here) ----
    if (w < 2){
        const int g = w;
        const int b = b_base + g;
        // Phase B
        {
            const int p = lane >> 3, o = lane & 7;
            const int l0 = (0x64204501u >> (p * 4)) & 15;
            const int l1 = (0x75316723u >> (p * 4)) & 15;
            sm.tl.pp[g][p * 16 + o]     = sm.tl.line[g][l0 * 16 + o]     + sm.tl.line[g][l1 * 16 + o];
            sm.tl.pp[g][p * 16 + o + 8] = sm.tl.line[g][l0 * 16 + o + 8] + sm.tl.line[g][l1 * 16 + o + 8];
        }
        __builtin_amdgcn_wave_barrier();
        // Phase C
        if (lane < 56){
            const int p  = lane / 7;
            const int qi = lane - p * 7;
            const int jl = qi + (qi >= p ? 1 : 0);
            float fmv[32];
            #pragma unroll
            for (int f = 0; f < 16; ++f){
                fmv[f]      = sm.tl.pp[g][p  * 16 + f];
                fmv[16 + f] = sm.tl.pp[g][jl * 16 + f];
            }
            const int rel = relation[p * 7 + qi] & 1;
            float ce[4];
            #pragma unroll
            for (int c = 0; c < 4; ++c) ce[c] = emb_const[rel * 4 + c];
            float m[20];
            for (int o = 0; o < 20; ++o){
                float xf = sm.tl.bcf[o];
                #pragma unroll
                for (int f = 0; f < 32; ++f) xf = fmaf(fmv[f], sm.tl.wcf[o * 32 + f], xf);
                float yc = sm.tl.bcc[o];
                #pragma unroll
                for (int c = 0; c < 4; ++c) yc = fmaf(ce[c], sm.tl.wcc[o * 4 + c], yc);
                m[o] = fmaxf(xf, 0.0f) * fmaxf(yc, 0.0f);
            }
            float fin = sm.tl.bfin;
            for (int o = 0; o < 20; ++o){
                float zz = sm.tl.bcm[o];
                #pragma unroll
                for (int c = 0; c < 20; ++c) zz = fmaf(m[c], sm.tl.wcm[o * 20 + c], zz);
                fin = fmaf(fmaxf(zz, 0.0f), sm.tl.wfin[o], fin);
            }
            sm.tl.line[g][lane] = fin;   // line dead after Phase B
        }
        __builtin_amdgcn_wave_barrier();
        if (lane < 8){
            float acc = 0.0f;
            #pragma unroll
            for (int qq = 0; qq < 7; ++qq) acc += sm.tl.line[g][lane * 7 + qq];
            out[b * 8 + lane] = acc;
        }
    }
}

extern "C" void kernel_launch(void* const* d_in, const int* in_sizes, int n_in,
                              void* d_out, int out_size, void* d_ws, size_t ws_size,
                              hipStream_t stream) {
    (void)n_in; (void)d_ws; (void)ws_size; (void)out_size;
    const float* feat      = (const float*)d_in[0];
    const float* hist      = (const float*)d_in[1];
    const int*   relation  = (const int*)d_in[2];
    const float* emb_phase = (const float*)d_in[3];
    const float* Wv        = (const float*)d_in[4];
    const float* bv        = (const float*)d_in[5];
    const float* Wh        = (const float*)d_in[6];
    const float* bh        = (const float*)d_in[7];
    const float* Wih       = (const float*)d_in[8];
    const float* Whh       = (const float*)d_in[9];
    const float* bih       = (const float*)d_in[10];
    const float* bhh       = (const float*)d_in[11];
    const float* Wl        = (const float*)d_in[12];
    const float* bl        = (const float*)d_in[13];
    const float* emb_const = (const float*)d_in[14];
    const float* Wcf       = (const float*)d_in[15];
    const float* bcf       = (const float*)d_in[16];
    const float* Wcc       = (const float*)d_in[17];
    const float* bcc       = (const float*)d_in[18];
    const float* Wcm       = (const float*)d_in[19];
    const float* bcm       = (const float*)d_in[20];
    const float* Wfin      = (const float*)d_in[21];
    const float* bfin      = (const float*)d_in[22];
    float* out = (float*)d_out;

    const int B = in_sizes[0] / 16;     // 2048
    const int nblocks = B / 2;          // 1024 blocks x 4 waves: row-split GRU
    FRAPRQ_fused_kernel<<<nblocks, 256, 0, stream>>>(
        feat, hist, relation, emb_phase, Wv, bv, Wh, bh, Wih, Whh, bih, bhh,
        Wl, bl, emb_const, Wcf, bcf, Wcc, bcc, Wcm, bcm, Wfin, bfin, out);
}

// Round 10
// 184.878 us; speedup vs baseline: 1.1072x; 1.0056x over previous
//
#include <hip/hip_runtime.h>

typedef unsigned short u16;
typedef unsigned int   u32;

typedef __attribute__((ext_vector_type(8))) short short8;   // 8 bf16 (4 VGPRs)
typedef __attribute__((ext_vector_type(4))) float f32x4;    // MFMA acc

union Frag { u32 u[4]; short8 s; };

__device__ __forceinline__ u32 fbits(float f){ union{float f;u32 u;}x; x.f=f; return x.u; }
__device__ __forceinline__ float bitsf(u32 u){ union{u32 u;float f;}x; x.u=u; return x.f; }
// HW packed f32->bf16 (RNE on gfx950): D = {lo16: cvt(a), hi16: cvt(b)}.
__device__ __forceinline__ u32 cvt_pk_bf16(float a, float b){
    u32 r;
    asm("v_cvt_pk_bf16_f32 %0, %1, %2" : "=v"(r) : "v"(a), "v"(b));
    return r;
}
__device__ __forceinline__ float sigmoidf_(float x){
    return __builtin_amdgcn_rcpf(1.0f + __expf(-x));
}

#define LOG2E 1.4426950408889634f

// Row-split GRU: 4 waves, wave w owns h rows 16w..16w+15, full K=64, no
// partial exchange. Single bf16 h (RNE) in ping-pong LDS; Whh/Wih keep hi/lo
// compensation; exp2-prescaled gates; cvt_pk packing; u prefetched across the
// barrier. Round-10 (critical-path shortening; counters show ~80% issue util
// with the rest latency on the per-step serial chain):
//  - MFMA chains tree-split: depth 5 -> 3 (+12 v_add_f32/step). f32
//    reassociation only; canary may drift ~1e-6.
//  - bu assembly via loop-invariant qoff b64 slice + 4 v_and masks
//    (replaces b128 read + 6 cndmask).
struct __align__(16) SharedMem {
    union {
        struct {                       // loop state: 20,992 B
            u16 hh[2][16][72];         // h bf16 (RNE), ping-pong [buf][seq][k]
            u32 uallp[64][16][4];      // packed u: {uh01,uh23,ul01,ul23} (16 KB)
        } lp;
        struct {                       // tail: 11,524 B
            float wl[1152];
            float bl[16];
            float wcf[640];
            float bcf[20];
            float wcc[80];
            float bcc[20];
            float wcm[400];
            float bcm[20];
            float wfin[20];
            float bfin;
            float line[2][128];
            float pp[2][128];
        } tl;
    };
    float h[16 * 68];                  // final h (f32) for the tail, 4352 B
};

__global__ __launch_bounds__(256, 4)
void FRAPRQ_fused_kernel(
    const float* __restrict__ feat,       // (B,16)
    const float* __restrict__ hist,       // (B,64,24)
    const int*   __restrict__ relation,   // (8,7)
    const float* __restrict__ emb_phase,  // (2,4)
    const float* __restrict__ Wv,         // (4,1)
    const float* __restrict__ bv,         // (4)
    const float* __restrict__ Wh,         // (4,3)
    const float* __restrict__ bh,         // (4)
    const float* __restrict__ Wih,        // (192,4)
    const float* __restrict__ Whh,        // (192,64)
    const float* __restrict__ bih,        // (192)
    const float* __restrict__ bhh,        // (192)
    const float* __restrict__ Wl,         // (16,72)
    const float* __restrict__ bl,         // (16)
    const float* __restrict__ emb_const,  // (2,4)
    const float* __restrict__ Wcf,        // (20,32)
    const float* __restrict__ bcf,        // (20)
    const float* __restrict__ Wcc,        // (20,4)
    const float* __restrict__ bcc,        // (20)
    const float* __restrict__ Wcm,        // (20,20)
    const float* __restrict__ bcm,        // (20)
    const float* __restrict__ Wfin,      // (1,20)
    const float* __restrict__ bfin,      // (1)
    float* __restrict__ out)             // (B,8)
{
    __shared__ SharedMem sm;
    const int tid  = threadIdx.x;        // 0..255
    const int w    = tid >> 6;           // wave 0..3: owns h rows 16w..16w+15
    const int lane = tid & 63;
    const int sq   = lane & 15;          // MFMA column: local seq (2 b's x 8 lanes)
    const int q    = lane >> 4;          // MFMA quad
    const int b_base = blockIdx.x * 2;

    // ---- cooperative staging ----
    {   // zero both h ping-pong buffers (h(-1) = 0): 1152 u32
        u32* z = (u32*)&sm.lp.hh[0][0][0];
        #pragma unroll 1
        for (int i = tid; i < 1152; i += 256) z[i] = 0u;
    }

    // ---- u precompute + bf16 hi/lo pack: thread = (seq s, t-group) ----
    {
        const int s  = tid & 15;         // seq
        const int tg = tid >> 4;         // 0..15 -> t = 4*tg + i
        const int bs_ = b_base + (s >> 3), ls_ = s & 7;
        const float* hbp = hist + (size_t)bs_ * 1536;
        float whc[12], bhc[4];
        #pragma unroll
        for (int c = 0; c < 4; ++c){
            whc[c*3+0] = Wh[c*3+0]; whc[c*3+1] = Wh[c*3+1]; whc[c*3+2] = Wh[c*3+2];
            bhc[c] = bh[c];
        }
        #pragma unroll
        for (int i = 0; i < 4; ++i){
            const int t = tg * 4 + i;
            const float x0 = hbp[t*24 + ls_];
            const float x1 = hbp[t*24 + ls_ + 8];
            const float x2 = hbp[t*24 + ls_ + 16];
            float u_[4];
            #pragma unroll
            for (int c = 0; c < 4; ++c)
                u_[c] = sigmoidf_(fmaf(whc[c*3], x0, fmaf(whc[c*3+1], x1, fmaf(whc[c*3+2], x2, bhc[c]))));
            const u32 uh01 = cvt_pk_bf16(u_[0], u_[1]);
            const u32 uh23 = cvt_pk_bf16(u_[2], u_[3]);
            const float l0 = u_[0] - bitsf((uh01 & 0xFFFFu) << 16);
            const float l1 = u_[1] - bitsf(uh01 & 0xFFFF0000u);
            const float l2 = u_[2] - bitsf((uh23 & 0xFFFFu) << 16);
            const float l3 = u_[3] - bitsf(uh23 & 0xFFFF0000u);
            *(uint4*)&sm.lp.uallp[t][s][0] =
                make_uint4(uh01, uh23, cvt_pk_bf16(l0, l1), cvt_pk_bf16(l2, l3));
        }
    }

    // gate scales: r/z sigmoid(x)=rcp(1+exp2(-log2e*x)); n tanh via +2log2e
    const float gsc[3] = { -LOG2E, -LOG2E, 2.0f * LOG2E };

    // ---- Whh A-fragments (prescaled): gate g3 x K-chunk c; idx = 2*g3+c ----
    Frag ahi[6], alo[6];
    #pragma unroll
    for (int g3 = 0; g3 < 3; ++g3){
        #pragma unroll
        for (int c = 0; c < 2; ++c){
            const int idx = g3 * 2 + c;
            const float* wp = Whh + (64 * g3 + 16 * w + sq) * 64 + 32 * c + 8 * q;
            const float4 fA = *(const float4*)wp;
            const float4 fB = *(const float4*)(wp + 4);
            const float s3 = gsc[g3];
            const float f[8] = {fA.x*s3, fA.y*s3, fA.z*s3, fA.w*s3,
                                fB.x*s3, fB.y*s3, fB.z*s3, fB.w*s3};
            #pragma unroll
            for (int p = 0; p < 4; ++p){
                const u32 hi = cvt_pk_bf16(f[2*p], f[2*p+1]);
                ahi[idx].u[p] = hi;
                const float l0 = f[2*p]   - bitsf((hi & 0xFFFFu) << 16);
                const float l1 = f[2*p+1] - bitsf(hi & 0xFFFF0000u);
                alo[idx].u[p] = cvt_pk_bf16(l0, l1);
            }
        }
    }

    // ---- Wih A-fragments (prescaled, hi/lo folded along K) ----
    // A[sq][k]: k0..3 = whi, k4..7 = wlo, k8..11 = whi, rest 0.
    Frag auR, auZ, auN;
    {
        Frag* dst[3] = { &auR, &auZ, &auN };
        #pragma unroll
        for (int g3 = 0; g3 < 3; ++g3){
            const int row = 64 * g3 + 16 * w + sq;
            const float4 wv4 = *(const float4*)&Wih[row * 4];
            const float s3 = gsc[g3];
            const float v0 = wv4.x*s3, v1 = wv4.y*s3, v2 = wv4.z*s3, v3 = wv4.w*s3;
            const u32 whi01 = cvt_pk_bf16(v0, v1);
            const u32 whi23 = cvt_pk_bf16(v2, v3);
            const float r0 = v0 - bitsf((whi01 & 0xFFFFu) << 16);
            const float r1 = v1 - bitsf(whi01 & 0xFFFF0000u);
            const float r2 = v2 - bitsf((whi23 & 0xFFFFu) << 16);
            const float r3 = v3 - bitsf(whi23 & 0xFFFF0000u);
            const u32 wlo01 = cvt_pk_bf16(r0, r1);
            const u32 wlo23 = cvt_pk_bf16(r2, r3);
            dst[g3]->u[0] = (q <= 1) ? whi01 : 0u;
            dst[g3]->u[1] = (q <= 1) ? whi23 : 0u;
            dst[g3]->u[2] = (q == 0) ? wlo01 : 0u;
            dst[g3]->u[3] = (q == 0) ? wlo23 : 0u;
        }
    }

    // ---- per-lane bias C-vectors (prescaled) for rows j = 16w+4q+r ----
    f32x4 bR4, bZ4, bNh4, bNi4;
    #pragma unroll
    for (int r = 0; r < 4; ++r){
        const int j = 16 * w + 4 * q + r;
        bR4[r]  = -LOG2E * (bih[j]       + bhh[j]);
        bZ4[r]  = -LOG2E * (bih[64 + j]  + bhh[64 + j]);
        bNi4[r] = 2.0f * LOG2E * bih[128 + j];
        bNh4[r] = 2.0f * LOG2E * bhh[128 + j];
    }

    // bu assembly constants (loop-invariant): per-lane b64 slice + AND masks.
    // q==0 reads {uh01,uh23}; q==1 reads {ul01,ul23}; q>=2 reads [0] masked.
    const int qoff = (q == 1) ? 2 : 0;
    const u32 m01 = (q <= 1) ? 0xFFFFFFFFu : 0u;   // k 8q..8q+7 live for q<2
    const u32 m2  = (q == 0) ? 0xFFFFFFFFu : 0u;   // k 8..11 (ulo) only q==0

    float hreg[4] = {0.f, 0.f, 0.f, 0.f};

    __syncthreads();   // staging + h init + uallp visible

    #define MFMA_(A,B,C) __builtin_amdgcn_mfma_f32_16x16x32_bf16(A, B, C, 0, 0, 0)
    const f32x4 zero4 = {0.f, 0.f, 0.f, 0.f};

    // One GRU step, RB a literal. UC0/UC1 = this step's u b64 slice
    // (pre-loaded); UN0/UN1 loaded here for t+1 (read-only across barrier).
    // Tree-split chains: depth 3 (u + bh0 hi/lo) || depth 2 (bh1 hi/lo).
    #define STEP_BODY(T, RB, UC0, UC1, UN0, UN1) { \
        const short8 bh0 = *(const short8*)&sm.lp.hh[RB][sq][8 * q]; \
        const short8 bh1 = *(const short8*)&sm.lp.hh[RB][sq][32 + 8 * q]; \
        { const int tn = ((T) < 63) ? (T) + 1 : 63; \
          const uint2 un = *(const uint2*)&sm.lp.uallp[tn][sq][qoff]; \
          UN0 = un.x; UN1 = un.y; } \
        Frag bu; \
        bu.u[0] = UC0 & m01; \
        bu.u[1] = UC1 & m01; \
        bu.u[2] = UC0 & m2; \
        bu.u[3] = UC1 & m2; \
        __builtin_amdgcn_s_setprio(1); \
        f32x4 aR1 = MFMA_(auR.s, bu.s, bR4); \
        aR1 = MFMA_(ahi[0].s, bh0, aR1); aR1 = MFMA_(alo[0].s, bh0, aR1); \
        f32x4 aR2 = MFMA_(ahi[1].s, bh1, zero4); aR2 = MFMA_(alo[1].s, bh1, aR2); \
        f32x4 aZ1 = MFMA_(auZ.s, bu.s, bZ4); \
        aZ1 = MFMA_(ahi[2].s, bh0, aZ1); aZ1 = MFMA_(alo[2].s, bh0, aZ1); \
        f32x4 aZ2 = MFMA_(ahi[3].s, bh1, zero4); aZ2 = MFMA_(alo[3].s, bh1, aZ2); \
        f32x4 aN1 = MFMA_(ahi[4].s, bh0, bNh4); aN1 = MFMA_(alo[4].s, bh0, aN1); \
        f32x4 aN2 = MFMA_(ahi[5].s, bh1, zero4); aN2 = MFMA_(alo[5].s, bh1, aN2); \
        f32x4 gN = MFMA_(auN.s, bu.s, bNi4); \
        __builtin_amdgcn_s_setprio(0); \
        float hn4[4]; \
        _Pragma("unroll") \
        for (int r = 0; r < 4; ++r){ \
            const float aRv = aR1[r] + aR2[r]; \
            const float aZv = aZ1[r] + aZ2[r]; \
            const float aNv = aN1[r] + aN2[r]; \
            const float rr   = __builtin_amdgcn_rcpf(1.0f + __builtin_amdgcn_exp2f(aRv)); \
            const float zz   = __builtin_amdgcn_rcpf(1.0f + __builtin_amdgcn_exp2f(aZv)); \
            const float y    = fmaf(rr, aNv, gN[r]); \
            const float cand = fmaf(-2.0f, \
                __builtin_amdgcn_rcpf(__builtin_amdgcn_exp2f(y) + 1.0f), 1.0f); \
            const float hn   = fmaf(zz, hreg[r] - cand, cand); \
            hreg[r] = hn; \
            hn4[r] = hn; \
        } \
        { \
            const u32 hi0 = cvt_pk_bf16(hn4[0], hn4[1]); \
            const u32 hi1 = cvt_pk_bf16(hn4[2], hn4[3]); \
            *(uint2*)&sm.lp.hh[(RB)^1][sq][16 * w + 4 * q] = make_uint2(hi0, hi1); \
        } \
        __syncthreads(); \
    }

    u32 uA0, uA1, uB0, uB1;
    { const uint2 u0 = *(const uint2*)&sm.lp.uallp[0][sq][qoff];
      uA0 = u0.x; uA1 = u0.y; }
    #pragma unroll 1
    for (int tt = 0; tt < 32; ++tt){
        STEP_BODY(2*tt,     0, uA0, uA1, uB0, uB1)
        STEP_BODY(2*tt + 1, 1, uB0, uB1, uA0, uA1)
    }
    #undef STEP_BODY
    #undef MFMA_

    // ---- final h (f32) for the tail, straight from registers ----
    {
        const float4 hv = make_float4(hreg[0], hreg[1], hreg[2], hreg[3]);
        *(float4*)&sm.h[sq * 68 + 16 * w + 4 * q] = hv;
    }

    // ---- stage tail weights into the (dead) loop region ----
    for (int i = tid; i < 1152; i += 256) sm.tl.wl[i]  = Wl[i];
    for (int i = tid; i <  640; i += 256) sm.tl.wcf[i] = Wcf[i];
    for (int i = tid; i <  400; i += 256) sm.tl.wcm[i] = Wcm[i];
    if (tid < 80) sm.tl.wcc[tid] = Wcc[tid];
    if (tid < 20){
        sm.tl.bcf[tid]  = bcf[tid];
        sm.tl.bcc[tid]  = bcc[tid];
        sm.tl.bcm[tid]  = bcm[tid];
        sm.tl.wfin[tid] = Wfin[tid];
    }
    if (tid < 16) sm.tl.bl[tid] = bl[tid];
    if (tid == 0) sm.tl.bfin = bfin[0];
    __syncthreads();   // h writes + tail weights visible

    // ---- tail Phase A: wave (g = w&1) x (half = w>>1); 8 outputs/wave ----
    {
        const int g    = w & 1;
        const int half = w >> 1;
        const int b    = b_base + g;
        const int l = lane >> 3, o = lane & 7;
        float fv[8];
        const float vraw = feat[b * 16 + 8 + l];
        const int   bit  = ((int)feat[b * 16 + l]) & 1;
        #pragma unroll
        for (int c = 0; c < 4; ++c){
            fv[c]     = sigmoidf_(fmaf(vraw, Wv[c], bv[c]));
            fv[4 + c] = sigmoidf_(emb_phase[bit * 4 + c]);
        }
        const float* hrow = &sm.h[(g * 8 + l) * 68];
        const int oo = o + half * 8;
        float acc = sm.tl.bl[oo];
        #pragma unroll
        for (int f = 0; f < 8; ++f) acc = fmaf(fv[f], sm.tl.wl[oo * 72 + f], acc);
        for (int k = 0; k < 64; ++k) acc = fmaf(hrow[k], sm.tl.wl[oo * 72 + 8 + k], acc);
        sm.tl.line[g][l * 16 + oo] = fmaxf(acc, 0.0f);
    }
    __syncthreads();   // line written by wave pairs {g, g+2}

    // ---- Phases B/C/out: waves 0,1 only (wave-private from here) ----
    if (w < 2){
        const int g = w;
        const int b = b_base + g;
        // Phase B
        {
            const int p = lane >> 3, o = lane & 7;
            const int l0 = (0x64204501u >> (p * 4)) & 15;
            const int l1 = (0x75316723u >> (p * 4)) & 15;
            sm.tl.pp[g][p * 16 + o]     = sm.tl.line[g][l0 * 16 + o]     + sm.tl.line[g][l1 * 16 + o];
            sm.tl.pp[g][p * 16 + o + 8] = sm.tl.line[g][l0 * 16 + o + 8] + sm.tl.line[g][l1 * 16 + o + 8];
        }
        __builtin_amdgcn_wave_barrier();
        // Phase C
        if (lane < 56){
            const int p  = lane / 7;
            const int qi = lane - p * 7;
            const int jl = qi + (qi >= p ? 1 : 0);
            float fmv[32];
            #pragma unroll
            for (int f = 0; f < 16; ++f){
                fmv[f]      = sm.tl.pp[g][p  * 16 + f];
                fmv[16 + f] = sm.tl.pp[g][jl * 16 + f];
            }
            const int rel = relation[p * 7 + qi] & 1;
            float ce[4];
            #pragma unroll
            for (int c = 0; c < 4; ++c) ce[c] = emb_const[rel * 4 + c];
            float m[20];
            for (int o = 0; o < 20; ++o){
                float xf = sm.tl.bcf[o];
                #pragma unroll
                for (int f = 0; f < 32; ++f) xf = fmaf(fmv[f], sm.tl.wcf[o * 32 + f], xf);
                float yc = sm.tl.bcc[o];
                #pragma unroll
                for (int c = 0; c < 4; ++c) yc = fmaf(ce[c], sm.tl.wcc[o * 4 + c], yc);
                m[o] = fmaxf(xf, 0.0f) * fmaxf(yc, 0.0f);
            }
            float fin = sm.tl.bfin;
            for (int o = 0; o < 20; ++o){
                float zz = sm.tl.bcm[o];
                #pragma unroll
                for (int c = 0; c < 20; ++c) zz = fmaf(m[c], sm.tl.wcm[o * 20 + c], zz);
                fin = fmaf(fmaxf(zz, 0.0f), sm.tl.wfin[o], fin);
            }
            sm.tl.line[g][lane] = fin;   // line dead after Phase B
        }
        __builtin_amdgcn_wave_barrier();
        if (lane < 8){
            float acc = 0.0f;
            #pragma unroll
            for (int qq = 0; qq < 7; ++qq) acc += sm.tl.line[g][lane * 7 + qq];
            out[b * 8 + lane] = acc;
        }
    }
}

extern "C" void kernel_launch(void* const* d_in, const int* in_sizes, int n_in,
                              void* d_out, int out_size, void* d_ws, size_t ws_size,
                              hipStream_t stream) {
    (void)n_in; (void)d_ws; (void)ws_size; (void)out_size;
    const float* feat      = (const float*)d_in[0];
    const float* hist      = (const float*)d_in[1];
    const int*   relation  = (const int*)d_in[2];
    const float* emb_phase = (const float*)d_in[3];
    const float* Wv        = (const float*)d_in[4];
    const float* bv        = (const float*)d_in[5];
    const float* Wh        = (const float*)d_in[6];
    const float* bh        = (const float*)d_in[7];
    const float* Wih       = (const float*)d_in[8];
    const float* Whh       = (const float*)d_in[9];
    const float* bih       = (const float*)d_in[10];
    const float* bhh       = (const float*)d_in[11];
    const float* Wl        = (const float*)d_in[12];
    const float* bl        = (const float*)d_in[13];
    const float* emb_const = (const float*)d_in[14];
    const float* Wcf       = (const float*)d_in[15];
    const float* bcf       = (const float*)d_in[16];
    const float* Wcc       = (const float*)d_in[17];
    const float* bcc       = (const float*)d_in[18];
    const float* Wcm       = (const float*)d_in[19];
    const float* bcm       = (const float*)d_in[20];
    const float* Wfin      = (const float*)d_in[21];
    const float* bfin      = (const float*)d_in[22];
    float* out = (float*)d_out;

    const int B = in_sizes[0] / 16;     // 2048
    const int nblocks = B / 2;          // 1024 blocks x 4 waves: row-split GRU
    FRAPRQ_fused_kernel<<<nblocks, 256, 0, stream>>>(
        feat, hist, relation, emb_phase, Wv, bv, Wh, bh, Wih, Whh, bih, bhh,
        Wl, bl, emb_const, Wcf, bcf, Wcc, bcc, Wcm, bcm, Wfin, bfin, out);
}